// Round 7
// baseline (112.521 us; speedup 1.0000x reference)
//
#include <hip/hip_runtime.h>
#include <math.h>

#define BB 32
#define LL 1024
#define DIMM 64
#define DINN 256
#define NHEADS 4
#define DSTATE 16
#define DINPROJ 548
#define EPSF 1e-5f
#define NCH 16    // chunks per sequence
#define CS 64     // chunk size

typedef __attribute__((ext_vector_type(8))) short bf16x8;
typedef __attribute__((ext_vector_type(4))) float f32x4;

__device__ inline ushort f2bf(float f) {
    union { float f; unsigned u; } v; v.f = f;
    unsigned r = (v.u + 0x7FFFu + ((v.u >> 16) & 1u)) >> 16;
    return (ushort)r;
}
__device__ inline float bf2f(ushort u) {
    union { float f; unsigned u; } v; v.u = ((unsigned)u) << 16; return v.f;
}

// ---------------- K0: convert weights to bf16 ----------------
__global__ __launch_bounds__(256) void kwcvt(
        const float* __restrict__ Win, const float* __restrict__ Wout,
        ushort* __restrict__ Wb, ushort* __restrict__ Wob) {
    int i = blockIdx.x * 256 + threadIdx.x;
    if (i < DINPROJ * 64) Wb[i] = f2bf(Win[i]);
    else if (i < DINPROJ * 64 + 64 * DINN) {
        int j = i - DINPROJ * 64;
        Wob[j] = f2bf(Wout[j]);
    }
}

// ------- K1: RMSNorm + in_proj (bf16 MFMA) -> zbuf (bf16) + xbcbuf (bf16) -------
__global__ __launch_bounds__(256) void k1_mfma(
        const float* __restrict__ x, const ushort* __restrict__ Wb,
        const float* __restrict__ bnw, ushort* __restrict__ zbuf,
        ushort* __restrict__ xbcbuf) {
    __shared__ float u[32][68];
    __shared__ float rstd[32];
    const int t = threadIdx.x;
    const int m0 = blockIdx.x * 32;
    const float* xrow = x + (size_t)m0 * 64;
    #pragma unroll
    for (int i = 0; i < 2; ++i) {
        int idx = t + i * 256;
        float4 v = ((const float4*)xrow)[idx];
        *(float4*)&u[idx >> 4][(idx & 15) * 4] = v;
    }
    __syncthreads();
    {
        int row = t >> 3, part = t & 7;
        float s = 0.f;
        #pragma unroll
        for (int j = 0; j < 8; ++j) { float v = u[row][part * 8 + j]; s = fmaf(v, v, s); }
        s += __shfl_xor(s, 1); s += __shfl_xor(s, 2); s += __shfl_xor(s, 4);
        if (part == 0) rstd[row] = rsqrtf(s * (1.f / 64.f) + EPSF);
    }
    __syncthreads();

    const int w = t >> 6, l = t & 63;
    const int a = l & 15, kb = (l >> 4) * 8;

    float4 bw[2][2];
    bw[0][0] = *(const float4*)&bnw[kb];
    bw[0][1] = *(const float4*)&bnw[kb + 4];
    bw[1][0] = *(const float4*)&bnw[32 + kb];
    bw[1][1] = *(const float4*)&bnw[32 + kb + 4];

    bf16x8 af[2][2];
    #pragma unroll
    for (int mt = 0; mt < 2; ++mt) {
        float rs = rstd[mt * 16 + a];
        #pragma unroll
        for (int kk = 0; kk < 2; ++kk) {
            float4 v0 = *(const float4*)&u[mt * 16 + a][kk * 32 + kb];
            float4 v1 = *(const float4*)&u[mt * 16 + a][kk * 32 + kb + 4];
            ushort* p = (ushort*)&af[mt][kk];
            p[0] = f2bf(v0.x * rs * bw[kk][0].x);
            p[1] = f2bf(v0.y * rs * bw[kk][0].y);
            p[2] = f2bf(v0.z * rs * bw[kk][0].z);
            p[3] = f2bf(v0.w * rs * bw[kk][0].w);
            p[4] = f2bf(v1.x * rs * bw[kk][1].x);
            p[5] = f2bf(v1.y * rs * bw[kk][1].y);
            p[6] = f2bf(v1.z * rs * bw[kk][1].z);
            p[7] = f2bf(v1.w * rs * bw[kk][1].w);
        }
    }

    for (int nt = w; nt < 34; nt += 4) {
        const ushort* wbp = Wb + (size_t)(nt * 16 + a) * 64 + kb;
        bf16x8 b0 = *(const bf16x8*)wbp;
        bf16x8 b1 = *(const bf16x8*)(wbp + 32);
        #pragma unroll
        for (int mt = 0; mt < 2; ++mt) {
            f32x4 acc = {0.f, 0.f, 0.f, 0.f};
            acc = __builtin_amdgcn_mfma_f32_16x16x32_bf16(af[mt][0], b0, acc, 0, 0, 0);
            acc = __builtin_amdgcn_mfma_f32_16x16x32_bf16(af[mt][1], b1, acc, 0, 0, 0);
            int row0 = m0 + mt * 16 + (l >> 4) * 4;
            int col = nt * 16 + a;
            if (nt < 16) {
                ushort* orow = zbuf + (size_t)row0 * DINN + col;
                #pragma unroll
                for (int r = 0; r < 4; ++r) orow[(size_t)r * DINN] = f2bf(acc[r]);
            } else {
                ushort* orow = xbcbuf + (size_t)row0 * 288 + (col - 256);
                #pragma unroll
                for (int r = 0; r < 4; ++r) orow[(size_t)r * 288] = f2bf(acc[r]);
            }
        }
    }
}

// ------- K1b: dt columns in pure fp32 + softplus -> dtbuf [B][H][L] -------
__global__ __launch_bounds__(256) void kdt(
        const float* __restrict__ x, const float* __restrict__ W,
        const float* __restrict__ bnw, const float* __restrict__ dt_bias,
        float* __restrict__ dtbuf) {
    __shared__ float u[64][68];
    __shared__ float wdt[4][64];
    __shared__ float rstd[64];
    const int t = threadIdx.x;
    const int m0 = blockIdx.x * 64;
    const float* xrow = x + (size_t)m0 * 64;
    #pragma unroll
    for (int i = 0; i < 4; ++i) {
        int idx = t + i * 256;
        float4 v = ((const float4*)xrow)[idx];
        *(float4*)&u[idx >> 4][(idx & 15) * 4] = v;
    }
    wdt[t >> 6][t & 63] = W[(size_t)(544 + (t >> 6)) * 64 + (t & 63)] * bnw[t & 63];
    __syncthreads();
    {
        int row = t >> 2, part = t & 3;
        float s = 0.f;
        #pragma unroll
        for (int j = 0; j < 16; ++j) { float v = u[row][part * 16 + j]; s = fmaf(v, v, s); }
        s += __shfl_xor(s, 1); s += __shfl_xor(s, 2);
        if (part == 0) rstd[row] = rsqrtf(s * (1.f / 64.f) + EPSF);
    }
    __syncthreads();
    const int row = t >> 2, h = t & 3;
    const int b = m0 >> 10, lofs = (m0 & 1023) + row;
    const float* ur = u[row];
    const float* wr = wdt[h];
    float s = 0.f;
    #pragma unroll
    for (int k4 = 0; k4 < 16; ++k4) {
        float4 uv = *(const float4*)&ur[k4 * 4];
        float4 wv = *(const float4*)&wr[k4 * 4];
        s = fmaf(uv.x, wv.x, s); s = fmaf(uv.y, wv.y, s);
        s = fmaf(uv.z, wv.z, s); s = fmaf(uv.w, wv.w, s);
    }
    s = s * rstd[row] + dt_bias[h];
    s = fmaxf(s, 0.f) + log1pf(expf(-fabsf(s)));
    dtbuf[((size_t)(b * 4 + h)) * LL + lofs] = s;
}

// ---------------- K3a: SSD chunked scan via MFMA (bf16 in/out) ----------------
// grid 2048 = (b,h,c); block 256 = 4 waves
__global__ __launch_bounds__(256) void k3a_ssd(
        const ushort* __restrict__ xbcbuf, const float* __restrict__ dtbuf,
        const float* __restrict__ conv_w, const float* __restrict__ conv_b,
        const float* __restrict__ A_log, const float* __restrict__ Dp,
        ushort* __restrict__ y, float* __restrict__ h0buf,
        float* __restrict__ cdecbuf, float* __restrict__ Cpost) {
    const int bid = blockIdx.x;
    const int c = bid & 15, h = (bid >> 4) & 3, b = bid >> 6;
    const int t = threadIdx.x;

    __shared__ union {
        struct { ushort rawx[67][64]; ushort rawbc[67][32]; } st;  // 12.9 KB
        struct { ushort Mb[64][72]; ushort BwT[16][72]; } ssd;     // 11.5 KB
    } uu;
    __shared__ ushort XbT[64][72];   // x transposed [chan][token], bf16
    __shared__ ushort Bb[64][40];    // [token][state(16) pad->40]
    __shared__ ushort Cb[64][40];
    __shared__ float dtt[64], laa[64], ww[64];

    const float A  = -expf(A_log[h]);
    const float Dh = Dp[h];
    const int l0 = c * CS;
    const ushort* xb = xbcbuf + (size_t)b * LL * 288;   // per-batch base

    // ---- phase 1: stage raw (bf16) + zero pads + dt/la scan ----
    for (int i = t; i < 67 * 32; i += 256) {
        int r = i >> 5, cu = i & 31;
        int l = l0 - 3 + r;
        ((uint*)&uu.st.rawx[r][0])[cu] =
            (l >= 0) ? ((const uint*)(xb + (size_t)l * 288 + h * 64))[cu] : 0u;
    }
    for (int i = t; i < 67 * 16; i += 256) {
        int r = i >> 4, cu = i & 15;
        int l = l0 - 3 + r;
        ((uint*)&uu.st.rawbc[r][0])[cu] =
            (l >= 0) ? ((const uint*)(xb + (size_t)l * 288 + 256))[cu] : 0u;
    }
    {
        uint* pz = (uint*)&Bb[0][0];
        for (int i = t; i < 64 * 40 / 2; i += 256) pz[i] = 0;
        uint* pz2 = (uint*)&Cb[0][0];
        for (int i = t; i < 64 * 40 / 2; i += 256) pz2[i] = 0;
    }
    if (t < 64) {
        float dv = dtbuf[((size_t)(b * 4 + h)) * LL + l0 + t];  // softplus'ed dt
        float run = dv * A;
        #pragma unroll
        for (int off = 1; off < 64; off <<= 1) {
            float o = __shfl_up(run, off, 64);
            if (t >= off) run += o;
        }
        dtt[t] = dv;
        laa[t] = run;
        cdecbuf[((size_t)(b * 4 + h)) * LL + l0 + t] = expf(run);
        float laEnd = __shfl(run, 63, 64);
        ww[t] = dv * expf(laEnd - run);
    }
    __syncthreads();

    // ---- phase 2: conv + SiLU -> bf16 tiles ----
    {
        const int jx = t & 63;
        const int cx = h * 64 + jx;
        const float4 cwx = *(const float4*)&conv_w[cx * 4];
        const float  cbx = conv_b[cx];
        #pragma unroll
        for (int i = 0; i < 16; ++i) {
            int s = (t >> 6) + i * 4;
            float v = cbx + bf2f(uu.st.rawx[s][jx]) * cwx.x
                          + bf2f(uu.st.rawx[s + 1][jx]) * cwx.y
                          + bf2f(uu.st.rawx[s + 2][jx]) * cwx.z
                          + bf2f(uu.st.rawx[s + 3][jx]) * cwx.w;
            v = v / (1.f + expf(-v));
            XbT[jx][s] = f2bf(v);
        }
        const int jbc = t & 31, cbc = 256 + jbc;
        const float4 cwb = *(const float4*)&conv_w[cbc * 4];
        const float  cbb = conv_b[cbc];
        #pragma unroll
        for (int i = 0; i < 8; ++i) {
            int s = (t >> 5) + i * 8;
            float v = cbb + bf2f(uu.st.rawbc[s][jbc]) * cwb.x
                          + bf2f(uu.st.rawbc[s + 1][jbc]) * cwb.y
                          + bf2f(uu.st.rawbc[s + 2][jbc]) * cwb.z
                          + bf2f(uu.st.rawbc[s + 3][jbc]) * cwb.w;
            v = v / (1.f + expf(-v));
            if (jbc < 16) Bb[s][jbc] = f2bf(v);
            else {
                Cb[s][jbc - 16] = f2bf(v);
                Cpost[((size_t)b * LL + l0 + s) * DSTATE + (jbc - 16)] = v;
            }
        }
    }
    __syncthreads();

    const int w = t >> 6, l = t & 63;
    const int fr = l & 15, fq = l >> 4;

    // ---- phase 3: G = C.B^T (K=32 padded), mask -> Mb; fill BwT ----
    f32x4 gacc[4];
    {
        bf16x8 ca = *(const bf16x8*)&Cb[w * 16 + fr][fq * 8];
        #pragma unroll
        for (int jt = 0; jt < 4; ++jt) {
            bf16x8 bb = *(const bf16x8*)&Bb[jt * 16 + fr][fq * 8];
            f32x4 z = {0.f, 0.f, 0.f, 0.f};
            gacc[jt] = __builtin_amdgcn_mfma_f32_16x16x32_bf16(ca, bb, z, 0, 0, 0);
        }
    }
    #pragma unroll
    for (int jt = 0; jt < 4; ++jt) {
        int j = jt * 16 + fr;
        float laj = laa[j], dtj = dtt[j];
        #pragma unroll
        for (int r = 0; r < 4; ++r) {
            int i = w * 16 + fq * 4 + r;
            float m = (j <= i) ? gacc[jt][r] * expf(laa[i] - laj) * dtj : 0.f;
            uu.ssd.Mb[i][j] = f2bf(m);
        }
    }
    #pragma unroll
    for (int i2 = 0; i2 < 4; ++i2) {
        int idx = t + i2 * 256;
        int n = idx & 15, jj = idx >> 4;
        uu.ssd.BwT[n][jj] = f2bf(ww[jj] * bf2f(Bb[jj][n]));
    }
    __syncthreads();

    // ---- phase 4: Y = M.X (+D skip, bf16 out) and S = X^T.(wB) ----
    {
        bf16x8 ma0 = *(const bf16x8*)&uu.ssd.Mb[w * 16 + fr][fq * 8];
        bf16x8 ma1 = *(const bf16x8*)&uu.ssd.Mb[w * 16 + fr][32 + fq * 8];
        ushort* ybase = y + ((size_t)b * LL + l0) * DINN + h * 64;
        #pragma unroll
        for (int pt = 0; pt < 4; ++pt) {
            bf16x8 xb0 = *(const bf16x8*)&XbT[pt * 16 + fr][fq * 8];
            bf16x8 xb1 = *(const bf16x8*)&XbT[pt * 16 + fr][32 + fq * 8];
            f32x4 acc = {0.f, 0.f, 0.f, 0.f};
            acc = __builtin_amdgcn_mfma_f32_16x16x32_bf16(ma0, xb0, acc, 0, 0, 0);
            acc = __builtin_amdgcn_mfma_f32_16x16x32_bf16(ma1, xb1, acc, 0, 0, 0);
            #pragma unroll
            for (int r = 0; r < 4; ++r) {
                int i = w * 16 + fq * 4 + r;
                int p = pt * 16 + fr;
                float xv = bf2f(XbT[p][i]);
                ybase[(size_t)i * DINN + p] = f2bf(acc[r] + Dh * xv);
            }
        }
    }
    if (c < 15) {
        bf16x8 xa0 = *(const bf16x8*)&XbT[w * 16 + fr][fq * 8];
        bf16x8 xa1 = *(const bf16x8*)&XbT[w * 16 + fr][32 + fq * 8];
        bf16x8 bw0 = *(const bf16x8*)&uu.ssd.BwT[fr][fq * 8];
        bf16x8 bw1 = *(const bf16x8*)&uu.ssd.BwT[fr][32 + fq * 8];
        f32x4 acc = {0.f, 0.f, 0.f, 0.f};
        acc = __builtin_amdgcn_mfma_f32_16x16x32_bf16(xa0, bw0, acc, 0, 0, 0);
        acc = __builtin_amdgcn_mfma_f32_16x16x32_bf16(xa1, bw1, acc, 0, 0, 0);
        float* Sdst = h0buf + (((size_t)(b * 4 + h)) * NCH + (c + 1)) * 1024;
        #pragma unroll
        for (int r = 0; r < 4; ++r) {
            int p = w * 16 + fq * 4 + r;
            Sdst[p * 16 + fr] = acc[r];
        }
    }
}

// ---------------- K3b: chunk-level scan (16 chunks) ----------------
__global__ __launch_bounds__(256) void k3b_chunkscan(
        float* __restrict__ h0buf, const float* __restrict__ cdecbuf) {
    const int bh = blockIdx.x;
    const int t = threadIdx.x;
    float* base = h0buf + (size_t)bh * NCH * 1024;
    const float* cd = cdecbuf + (size_t)bh * LL;
    float4 run = {0.f, 0.f, 0.f, 0.f};
    *(float4*)&base[(size_t)t * 4] = run;
    #pragma unroll
    for (int c = 1; c < NCH; ++c) {
        float P = cd[c * CS - 1];
        float4 S = *(float4*)&base[(size_t)c * 1024 + t * 4];
        run.x = fmaf(run.x, P, S.x);
        run.y = fmaf(run.y, P, S.y);
        run.z = fmaf(run.z, P, S.z);
        run.w = fmaf(run.w, P, S.w);
        *(float4*)&base[(size_t)c * 1024 + t * 4] = run;
    }
}

// ------- K4: correction + gate + RMSNorm (register-resident) + out_proj -------
__global__ __launch_bounds__(256) void k4_out(
        const ushort* __restrict__ ybf, const ushort* __restrict__ zbuf,
        const float* __restrict__ ngw, const ushort* __restrict__ Wob,
        const float* __restrict__ x, const float* __restrict__ h0buf,
        const float* __restrict__ cdecbuf, const float* __restrict__ Cpost,
        float* __restrict__ out) {
    __shared__ float Cs[32][16];
    __shared__ float cds[32][4];
    __shared__ union { float h0s[4][64][16]; ushort gb[32][264]; } ua;  // 16.9 KB
    const int t = threadIdx.x;
    const int m0 = blockIdx.x * 32;
    const int b  = m0 >> 10;
    const int l0 = m0 & 1023;
    const int ck = l0 >> 6;
    const ushort* yb = ybf + (size_t)m0 * DINN;
    const ushort* zb = zbuf + (size_t)m0 * DINN;

    // stage h0 (4 heads), C, cdec
    #pragma unroll
    for (int i = 0; i < 4; ++i) {
        float4 v = *(const float4*)&h0buf[(((size_t)(b * 4 + i)) * NCH + ck) * 1024 + t * 4];
        ((float4*)ua.h0s)[i * 256 + t] = v;
    }
    if (t < 128) {
        int r = t >> 2, n0 = (t & 3) * 4;
        *(float4*)&Cs[r][n0] = *(const float4*)&Cpost[((size_t)b * LL + l0 + r) * DSTATE + n0];
    } else {
        int tt = t - 128;
        int r = tt >> 2, hh = tt & 3;
        cds[r][hh] = cdecbuf[((size_t)(b * 4 + hh)) * LL + l0 + r];
    }
    __syncthreads();

    // register-cache h0 for this thread's 4 channels
    const int ch4 = (t & 63) * 4;
    const int hh  = ch4 >> 6;
    const int p0  = ch4 & 63;
    float4 H[4][4];
    #pragma unroll
    for (int k = 0; k < 4; ++k)
        #pragma unroll
        for (int n4 = 0; n4 < 4; ++n4)
            H[k][n4] = *(const float4*)&ua.h0s[hh][p0 + k][n4 * 4];
    __syncthreads();   // protect union: all H loads done before gb writes

    const float4 ng4 = *(const float4*)&ngw[ch4];

    // gate + correction + RMSNorm, fully register-resident per row
    #pragma unroll
    for (int i = 0; i < 8; ++i) {
        int row = i * 4 + (t >> 6);            // row owned entirely by this wave
        ushort4 yu = *(const ushort4*)&yb[(size_t)row * DINN + ch4];
        ushort4 zu = *(const ushort4*)&zb[(size_t)row * DINN + ch4];
        float4 yv = { bf2f(yu.x), bf2f(yu.y), bf2f(yu.z), bf2f(yu.w) };
        float4 zv = { bf2f(zu.x), bf2f(zu.y), bf2f(zu.z), bf2f(zu.w) };
        float4 C0 = *(const float4*)&Cs[row][0];
        float4 C1 = *(const float4*)&Cs[row][4];
        float4 C2 = *(const float4*)&Cs[row][8];
        float4 C3 = *(const float4*)&Cs[row][12];
        float cdv = cds[row][hh];
        float corr[4];
        #pragma unroll
        for (int k = 0; k < 4; ++k) {
            float s = H[k][0].x * C0.x + H[k][0].y * C0.y + H[k][0].z * C0.z + H[k][0].w * C0.w;
            s += H[k][1].x * C1.x + H[k][1].y * C1.y + H[k][1].z * C1.z + H[k][1].w * C1.w;
            s += H[k][2].x * C2.x + H[k][2].y * C2.y + H[k][2].z * C2.z + H[k][2].w * C2.w;
            s += H[k][3].x * C3.x + H[k][3].y * C3.y + H[k][3].z * C3.z + H[k][3].w * C3.w;
            corr[k] = s * cdv;
        }
        yv.x += corr[0]; yv.y += corr[1]; yv.z += corr[2]; yv.w += corr[3];
        float4 gv;
        gv.x = yv.x * zv.x / (1.f + expf(-zv.x));
        gv.y = yv.y * zv.y / (1.f + expf(-zv.y));
        gv.z = yv.z * zv.z / (1.f + expf(-zv.z));
        gv.w = yv.w * zv.w / (1.f + expf(-zv.w));
        // wave all-reduce of sum of squares for this row (64 lanes x 4 cols)
        float s = gv.x * gv.x + gv.y * gv.y + gv.z * gv.z + gv.w * gv.w;
        s += __shfl_xor(s, 1);  s += __shfl_xor(s, 2);  s += __shfl_xor(s, 4);
        s += __shfl_xor(s, 8);  s += __shfl_xor(s, 16); s += __shfl_xor(s, 32);
        float rs = rsqrtf(s * (1.f / 256.f) + EPSF);
        ushort4 o;
        o.x = f2bf(gv.x * rs * ng4.x);
        o.y = f2bf(gv.y * rs * ng4.y);
        o.z = f2bf(gv.z * rs * ng4.z);
        o.w = f2bf(gv.w * rs * ng4.w);
        *(ushort4*)&ua.gb[row][ch4] = o;
    }
    __syncthreads();

    const int w = t >> 6, l = t & 63;
    const int j = l & 15, kb = (l >> 4) * 8;
    bf16x8 bf[8];
    #pragma unroll
    for (int ks = 0; ks < 8; ++ks)
        bf[ks] = *(const bf16x8*)&Wob[(size_t)(16 * w + j) * DINN + ks * 32 + kb];
    #pragma unroll
    for (int mt = 0; mt < 2; ++mt) {
        f32x4 acc = {0.f, 0.f, 0.f, 0.f};
        #pragma unroll
        for (int ks = 0; ks < 8; ++ks) {
            bf16x8 af = *(const bf16x8*)&ua.gb[mt * 16 + j][ks * 32 + kb];
            acc = __builtin_amdgcn_mfma_f32_16x16x32_bf16(af, bf[ks], acc, 0, 0, 0);
        }
        #pragma unroll
        for (int r = 0; r < 4; ++r) {
            size_t row = (size_t)m0 + mt * 16 + (l >> 4) * 4 + r;
            size_t oidx = row * 64 + 16 * w + j;
            out[oidx] = acc[r] + 2.f * x[oidx];
        }
    }
}

extern "C" void kernel_launch(void* const* d_in, const int* in_sizes, int n_in,
                              void* d_out, int out_size, void* d_ws, size_t ws_size,
                              hipStream_t stream) {
    const float* x          = (const float*)d_in[0];
    const float* in_proj_w  = (const float*)d_in[1];
    const float* conv_w     = (const float*)d_in[2];
    const float* conv_b     = (const float*)d_in[3];
    const float* dt_bias    = (const float*)d_in[4];
    const float* A_log      = (const float*)d_in[5];
    const float* D          = (const float*)d_in[6];
    const float* norm_gate  = (const float*)d_in[7];
    const float* out_proj_w = (const float*)d_in[8];
    const float* block_norm = (const float*)d_in[9];
    float* out = (float*)d_out;

    float* h0b   = (float*)d_ws;                               //  2,097,152 f32
    float* cdec  = h0b  + (size_t)BB * NHEADS * NCH * 1024;    //    131,072 f32
    float* Cp    = cdec + (size_t)BB * NHEADS * LL;            //    524,288 f32
    float* dtb   = Cp   + (size_t)BB * LL * DSTATE;            //    131,072 f32
    ushort* ybf  = (ushort*)(dtb + (size_t)BB * NHEADS * LL);  //  8,388,608 us
    ushort* zbuf = ybf  + (size_t)BB * LL * DINN;              //  8,388,608 us
    ushort* xbc  = zbuf + (size_t)BB * LL * DINN;              //  9,437,184 us
    ushort* Wb   = xbc  + (size_t)BB * LL * 288;               //     35,072 us
    ushort* Wob  = Wb   + (size_t)DINPROJ * 64;                //     16,384 us

    kwcvt<<<201, 256, 0, stream>>>(in_proj_w, out_proj_w, Wb, Wob);
    k1_mfma<<<1024, 256, 0, stream>>>(x, Wb, block_norm, zbuf, xbc);
    kdt<<<512, 256, 0, stream>>>(x, in_proj_w, block_norm, dt_bias, dtb);
    k3a_ssd<<<2048, 256, 0, stream>>>(xbc, dtb, conv_w, conv_b, A_log, D, ybf, h0b, cdec, Cp);
    k3b_chunkscan<<<128, 256, 0, stream>>>(h0b, cdec);
    k4_out<<<1024, 256, 0, stream>>>(ybf, zbuf, norm_gate, Wob, x, h0b, cdec, Cp, out);
}

// Round 8
// 90.834 us; speedup vs baseline: 1.2387x; 1.2387x over previous
//
#include <hip/hip_runtime.h>
#include <math.h>

#define BB 32
#define LL 1024
#define DIMM 64
#define DINN 256
#define NHEADS 4
#define DSTATE 16
#define DINPROJ 548
#define EPSF 1e-5f
#define NCH 16    // chunks per sequence
#define CS 64     // chunk size

typedef __attribute__((ext_vector_type(8))) short bf16x8;
typedef __attribute__((ext_vector_type(4))) float f32x4;

__device__ inline ushort f2bf(float f) {
    union { float f; unsigned u; } v; v.f = f;
    unsigned r = (v.u + 0x7FFFu + ((v.u >> 16) & 1u)) >> 16;
    return (ushort)r;
}
__device__ inline float bf2f(ushort u) {
    union { float f; unsigned u; } v; v.u = ((unsigned)u) << 16; return v.f;
}

// ---------------- K0: convert weights to bf16 ----------------
__global__ __launch_bounds__(256) void kwcvt(
        const float* __restrict__ Win, const float* __restrict__ Wout,
        ushort* __restrict__ Wb, ushort* __restrict__ Wob) {
    int i = blockIdx.x * 256 + threadIdx.x;
    if (i < DINPROJ * 64) Wb[i] = f2bf(Win[i]);
    else if (i < DINPROJ * 64 + 64 * DINN) {
        int j = i - DINPROJ * 64;
        Wob[j] = f2bf(Wout[j]);
    }
}

// ------- K1: RMSNorm + in_proj (bf16 MFMA) -> zbuf (bf16) + xbcbuf (bf16) -------
__global__ __launch_bounds__(256) void k1_mfma(
        const float* __restrict__ x, const ushort* __restrict__ Wb,
        const float* __restrict__ bnw, ushort* __restrict__ zbuf,
        ushort* __restrict__ xbcbuf) {
    __shared__ float u[32][68];
    __shared__ float rstd[32];
    const int t = threadIdx.x;
    const int m0 = blockIdx.x * 32;
    const float* xrow = x + (size_t)m0 * 64;
    #pragma unroll
    for (int i = 0; i < 2; ++i) {
        int idx = t + i * 256;
        float4 v = ((const float4*)xrow)[idx];
        *(float4*)&u[idx >> 4][(idx & 15) * 4] = v;
    }
    __syncthreads();
    {
        int row = t >> 3, part = t & 7;
        float s = 0.f;
        #pragma unroll
        for (int j = 0; j < 8; ++j) { float v = u[row][part * 8 + j]; s = fmaf(v, v, s); }
        s += __shfl_xor(s, 1); s += __shfl_xor(s, 2); s += __shfl_xor(s, 4);
        if (part == 0) rstd[row] = rsqrtf(s * (1.f / 64.f) + EPSF);
    }
    __syncthreads();

    const int w = t >> 6, l = t & 63;
    const int a = l & 15, kb = (l >> 4) * 8;

    float4 bw[2][2];
    bw[0][0] = *(const float4*)&bnw[kb];
    bw[0][1] = *(const float4*)&bnw[kb + 4];
    bw[1][0] = *(const float4*)&bnw[32 + kb];
    bw[1][1] = *(const float4*)&bnw[32 + kb + 4];

    bf16x8 af[2][2];
    #pragma unroll
    for (int mt = 0; mt < 2; ++mt) {
        float rs = rstd[mt * 16 + a];
        #pragma unroll
        for (int kk = 0; kk < 2; ++kk) {
            float4 v0 = *(const float4*)&u[mt * 16 + a][kk * 32 + kb];
            float4 v1 = *(const float4*)&u[mt * 16 + a][kk * 32 + kb + 4];
            ushort* p = (ushort*)&af[mt][kk];
            p[0] = f2bf(v0.x * rs * bw[kk][0].x);
            p[1] = f2bf(v0.y * rs * bw[kk][0].y);
            p[2] = f2bf(v0.z * rs * bw[kk][0].z);
            p[3] = f2bf(v0.w * rs * bw[kk][0].w);
            p[4] = f2bf(v1.x * rs * bw[kk][1].x);
            p[5] = f2bf(v1.y * rs * bw[kk][1].y);
            p[6] = f2bf(v1.z * rs * bw[kk][1].z);
            p[7] = f2bf(v1.w * rs * bw[kk][1].w);
        }
    }

    for (int nt = w; nt < 34; nt += 4) {
        const ushort* wbp = Wb + (size_t)(nt * 16 + a) * 64 + kb;
        bf16x8 b0 = *(const bf16x8*)wbp;
        bf16x8 b1 = *(const bf16x8*)(wbp + 32);
        #pragma unroll
        for (int mt = 0; mt < 2; ++mt) {
            f32x4 acc = {0.f, 0.f, 0.f, 0.f};
            acc = __builtin_amdgcn_mfma_f32_16x16x32_bf16(af[mt][0], b0, acc, 0, 0, 0);
            acc = __builtin_amdgcn_mfma_f32_16x16x32_bf16(af[mt][1], b1, acc, 0, 0, 0);
            int row0 = m0 + mt * 16 + (l >> 4) * 4;
            int col = nt * 16 + a;
            if (nt < 16) {
                ushort* orow = zbuf + (size_t)row0 * DINN + col;
                #pragma unroll
                for (int r = 0; r < 4; ++r) orow[(size_t)r * DINN] = f2bf(acc[r]);
            } else {
                ushort* orow = xbcbuf + (size_t)row0 * 288 + (col - 256);
                #pragma unroll
                for (int r = 0; r < 4; ++r) orow[(size_t)r * 288] = f2bf(acc[r]);
            }
        }
    }
}

// ------- K1b: dt columns in pure fp32 + softplus -> dtbuf [B][H][L] -------
__global__ __launch_bounds__(256) void kdt(
        const float* __restrict__ x, const float* __restrict__ W,
        const float* __restrict__ bnw, const float* __restrict__ dt_bias,
        float* __restrict__ dtbuf) {
    __shared__ float u[64][68];
    __shared__ float wdt[4][64];
    __shared__ float rstd[64];
    const int t = threadIdx.x;
    const int m0 = blockIdx.x * 64;
    const float* xrow = x + (size_t)m0 * 64;
    #pragma unroll
    for (int i = 0; i < 4; ++i) {
        int idx = t + i * 256;
        float4 v = ((const float4*)xrow)[idx];
        *(float4*)&u[idx >> 4][(idx & 15) * 4] = v;
    }
    wdt[t >> 6][t & 63] = W[(size_t)(544 + (t >> 6)) * 64 + (t & 63)] * bnw[t & 63];
    __syncthreads();
    {
        int row = t >> 2, part = t & 3;
        float s = 0.f;
        #pragma unroll
        for (int j = 0; j < 16; ++j) { float v = u[row][part * 16 + j]; s = fmaf(v, v, s); }
        s += __shfl_xor(s, 1); s += __shfl_xor(s, 2);
        if (part == 0) rstd[row] = rsqrtf(s * (1.f / 64.f) + EPSF);
    }
    __syncthreads();
    const int row = t >> 2, h = t & 3;
    const int b = m0 >> 10, lofs = (m0 & 1023) + row;
    const float* ur = u[row];
    const float* wr = wdt[h];
    float s = 0.f;
    #pragma unroll
    for (int k4 = 0; k4 < 16; ++k4) {
        float4 uv = *(const float4*)&ur[k4 * 4];
        float4 wv = *(const float4*)&wr[k4 * 4];
        s = fmaf(uv.x, wv.x, s); s = fmaf(uv.y, wv.y, s);
        s = fmaf(uv.z, wv.z, s); s = fmaf(uv.w, wv.w, s);
    }
    s = s * rstd[row] + dt_bias[h];
    s = fmaxf(s, 0.f) + log1pf(expf(-fabsf(s)));
    dtbuf[((size_t)(b * 4 + h)) * LL + lofs] = s;
}

// ---------------- K3a: SSD chunked scan via MFMA (bf16 in/out) ----------------
// grid 2048 = (b,h,c); block 256 = 4 waves
__global__ __launch_bounds__(256) void k3a_ssd(
        const ushort* __restrict__ xbcbuf, const float* __restrict__ dtbuf,
        const float* __restrict__ conv_w, const float* __restrict__ conv_b,
        const float* __restrict__ A_log, const float* __restrict__ Dp,
        ushort* __restrict__ y, float* __restrict__ h0buf,
        float* __restrict__ cdecbuf, float* __restrict__ Cpost) {
    const int bid = blockIdx.x;
    const int c = bid & 15, h = (bid >> 4) & 3, b = bid >> 6;
    const int t = threadIdx.x;

    __shared__ union {
        struct { ushort rawx[67][64]; ushort rawbc[67][32]; } st;  // 12.9 KB
        struct { ushort Mb[64][72]; ushort BwT[16][72]; } ssd;     // 11.5 KB
    } uu;
    __shared__ ushort XbT[64][72];   // x transposed [chan][token], bf16
    __shared__ ushort Bb[64][40];    // [token][state(16) pad->40]
    __shared__ ushort Cb[64][40];
    __shared__ float dtt[64], laa[64], ww[64];

    const float A  = -expf(A_log[h]);
    const float Dh = Dp[h];
    const int l0 = c * CS;
    const ushort* xb = xbcbuf + (size_t)b * LL * 288;   // per-batch base

    // ---- phase 1: stage raw (bf16) + zero pads + dt/la scan ----
    for (int i = t; i < 67 * 32; i += 256) {
        int r = i >> 5, cu = i & 31;
        int l = l0 - 3 + r;
        ((uint*)&uu.st.rawx[r][0])[cu] =
            (l >= 0) ? ((const uint*)(xb + (size_t)l * 288 + h * 64))[cu] : 0u;
    }
    for (int i = t; i < 67 * 16; i += 256) {
        int r = i >> 4, cu = i & 15;
        int l = l0 - 3 + r;
        ((uint*)&uu.st.rawbc[r][0])[cu] =
            (l >= 0) ? ((const uint*)(xb + (size_t)l * 288 + 256))[cu] : 0u;
    }
    {
        uint* pz = (uint*)&Bb[0][0];
        for (int i = t; i < 64 * 40 / 2; i += 256) pz[i] = 0;
        uint* pz2 = (uint*)&Cb[0][0];
        for (int i = t; i < 64 * 40 / 2; i += 256) pz2[i] = 0;
    }
    if (t < 64) {
        float dv = dtbuf[((size_t)(b * 4 + h)) * LL + l0 + t];  // softplus'ed dt
        float run = dv * A;
        #pragma unroll
        for (int off = 1; off < 64; off <<= 1) {
            float o = __shfl_up(run, off, 64);
            if (t >= off) run += o;
        }
        dtt[t] = dv;
        laa[t] = run;
        cdecbuf[((size_t)(b * 4 + h)) * LL + l0 + t] = expf(run);
        float laEnd = __shfl(run, 63, 64);
        ww[t] = dv * expf(laEnd - run);
    }
    __syncthreads();

    // ---- phase 2: conv + SiLU -> bf16 tiles ----
    {
        const int jx = t & 63;
        const int cx = h * 64 + jx;
        const float4 cwx = *(const float4*)&conv_w[cx * 4];
        const float  cbx = conv_b[cx];
        #pragma unroll
        for (int i = 0; i < 16; ++i) {
            int s = (t >> 6) + i * 4;
            float v = cbx + bf2f(uu.st.rawx[s][jx]) * cwx.x
                          + bf2f(uu.st.rawx[s + 1][jx]) * cwx.y
                          + bf2f(uu.st.rawx[s + 2][jx]) * cwx.z
                          + bf2f(uu.st.rawx[s + 3][jx]) * cwx.w;
            v = v / (1.f + expf(-v));
            XbT[jx][s] = f2bf(v);
        }
        const int jbc = t & 31, cbc = 256 + jbc;
        const float4 cwb = *(const float4*)&conv_w[cbc * 4];
        const float  cbb = conv_b[cbc];
        #pragma unroll
        for (int i = 0; i < 8; ++i) {
            int s = (t >> 5) + i * 8;
            float v = cbb + bf2f(uu.st.rawbc[s][jbc]) * cwb.x
                          + bf2f(uu.st.rawbc[s + 1][jbc]) * cwb.y
                          + bf2f(uu.st.rawbc[s + 2][jbc]) * cwb.z
                          + bf2f(uu.st.rawbc[s + 3][jbc]) * cwb.w;
            v = v / (1.f + expf(-v));
            if (jbc < 16) Bb[s][jbc] = f2bf(v);
            else {
                Cb[s][jbc - 16] = f2bf(v);
                Cpost[((size_t)b * LL + l0 + s) * DSTATE + (jbc - 16)] = v;
            }
        }
    }
    __syncthreads();

    const int w = t >> 6, l = t & 63;
    const int fr = l & 15, fq = l >> 4;

    // ---- phase 3: G = C.B^T (K=32 padded), mask -> Mb; fill BwT ----
    f32x4 gacc[4];
    {
        bf16x8 ca = *(const bf16x8*)&Cb[w * 16 + fr][fq * 8];
        #pragma unroll
        for (int jt = 0; jt < 4; ++jt) {
            bf16x8 bb = *(const bf16x8*)&Bb[jt * 16 + fr][fq * 8];
            f32x4 z = {0.f, 0.f, 0.f, 0.f};
            gacc[jt] = __builtin_amdgcn_mfma_f32_16x16x32_bf16(ca, bb, z, 0, 0, 0);
        }
    }
    #pragma unroll
    for (int jt = 0; jt < 4; ++jt) {
        int j = jt * 16 + fr;
        float laj = laa[j], dtj = dtt[j];
        #pragma unroll
        for (int r = 0; r < 4; ++r) {
            int i = w * 16 + fq * 4 + r;
            float m = (j <= i) ? gacc[jt][r] * expf(laa[i] - laj) * dtj : 0.f;
            uu.ssd.Mb[i][j] = f2bf(m);
        }
    }
    #pragma unroll
    for (int i2 = 0; i2 < 4; ++i2) {
        int idx = t + i2 * 256;
        int n = idx & 15, jj = idx >> 4;
        uu.ssd.BwT[n][jj] = f2bf(ww[jj] * bf2f(Bb[jj][n]));
    }
    __syncthreads();

    // ---- phase 4: Y = M.X (+D skip, bf16 out) and S = X^T.(wB) ----
    {
        bf16x8 ma0 = *(const bf16x8*)&uu.ssd.Mb[w * 16 + fr][fq * 8];
        bf16x8 ma1 = *(const bf16x8*)&uu.ssd.Mb[w * 16 + fr][32 + fq * 8];
        ushort* ybase = y + ((size_t)b * LL + l0) * DINN + h * 64;
        #pragma unroll
        for (int pt = 0; pt < 4; ++pt) {
            bf16x8 xb0 = *(const bf16x8*)&XbT[pt * 16 + fr][fq * 8];
            bf16x8 xb1 = *(const bf16x8*)&XbT[pt * 16 + fr][32 + fq * 8];
            f32x4 acc = {0.f, 0.f, 0.f, 0.f};
            acc = __builtin_amdgcn_mfma_f32_16x16x32_bf16(ma0, xb0, acc, 0, 0, 0);
            acc = __builtin_amdgcn_mfma_f32_16x16x32_bf16(ma1, xb1, acc, 0, 0, 0);
            #pragma unroll
            for (int r = 0; r < 4; ++r) {
                int i = w * 16 + fq * 4 + r;
                int p = pt * 16 + fr;
                float xv = bf2f(XbT[p][i]);
                ybase[(size_t)i * DINN + p] = f2bf(acc[r] + Dh * xv);
            }
        }
    }
    if (c < 15) {
        bf16x8 xa0 = *(const bf16x8*)&XbT[w * 16 + fr][fq * 8];
        bf16x8 xa1 = *(const bf16x8*)&XbT[w * 16 + fr][32 + fq * 8];
        bf16x8 bw0 = *(const bf16x8*)&uu.ssd.BwT[fr][fq * 8];
        bf16x8 bw1 = *(const bf16x8*)&uu.ssd.BwT[fr][32 + fq * 8];
        f32x4 acc = {0.f, 0.f, 0.f, 0.f};
        acc = __builtin_amdgcn_mfma_f32_16x16x32_bf16(xa0, bw0, acc, 0, 0, 0);
        acc = __builtin_amdgcn_mfma_f32_16x16x32_bf16(xa1, bw1, acc, 0, 0, 0);
        float* Sdst = h0buf + (((size_t)(b * 4 + h)) * NCH + (c + 1)) * 1024;
        #pragma unroll
        for (int r = 0; r < 4; ++r) {
            int p = w * 16 + fq * 4 + r;
            Sdst[p * 16 + fr] = acc[r];
        }
    }
}

// ---------------- K3b: chunk-level scan (16 chunks) ----------------
__global__ __launch_bounds__(256) void k3b_chunkscan(
        float* __restrict__ h0buf, const float* __restrict__ cdecbuf) {
    const int bh = blockIdx.x;
    const int t = threadIdx.x;
    float* base = h0buf + (size_t)bh * NCH * 1024;
    const float* cd = cdecbuf + (size_t)bh * LL;
    float4 run = {0.f, 0.f, 0.f, 0.f};
    *(float4*)&base[(size_t)t * 4] = run;
    #pragma unroll
    for (int c = 1; c < NCH; ++c) {
        float P = cd[c * CS - 1];
        float4 S = *(float4*)&base[(size_t)c * 1024 + t * 4];
        run.x = fmaf(run.x, P, S.x);
        run.y = fmaf(run.y, P, S.y);
        run.z = fmaf(run.z, P, S.z);
        run.w = fmaf(run.w, P, S.w);
        *(float4*)&base[(size_t)c * 1024 + t * 4] = run;
    }
}

// ------- K4: correction (H from global) + gate + RMSNorm + out_proj -------
__global__ __launch_bounds__(256) void k4_out(
        const ushort* __restrict__ ybf, const ushort* __restrict__ zbuf,
        const float* __restrict__ ngw, const ushort* __restrict__ Wob,
        const float* __restrict__ x, const float* __restrict__ h0buf,
        const float* __restrict__ cdecbuf, const float* __restrict__ Cpost,
        float* __restrict__ out) {
    __shared__ float Cs[32][16];
    __shared__ float cds[32][4];
    __shared__ ushort gb[32][264];      // 16.9 KB
    const int t = threadIdx.x;
    const int m0 = blockIdx.x * 32;
    const int b  = m0 >> 10;
    const int l0 = m0 & 1023;
    const int ck = l0 >> 6;
    const ushort* yb = ybf + (size_t)m0 * DINN;
    const ushort* zb = zbuf + (size_t)m0 * DINN;

    // stage C, cdec (small, broadcast-read later)
    if (t < 128) {
        int r = t >> 2, n0 = (t & 3) * 4;
        *(float4*)&Cs[r][n0] = *(const float4*)&Cpost[((size_t)b * LL + l0 + r) * DSTATE + n0];
    } else {
        int tt = t - 128;
        int r = tt >> 2, hh = tt & 3;
        cds[r][hh] = cdecbuf[((size_t)(b * 4 + hh)) * LL + l0 + r];
    }

    // H registers straight from global (L2-resident slab; no LDS round-trip)
    const int ch4 = (t & 63) * 4;
    const int hh  = ch4 >> 6;
    const int p0  = ch4 & 63;
    const float* hbase = h0buf + (((size_t)(b * 4 + hh)) * NCH + ck) * 1024 + p0 * 16;
    float4 H[4][4];
    #pragma unroll
    for (int k = 0; k < 4; ++k)
        #pragma unroll
        for (int n4 = 0; n4 < 4; ++n4)
            H[k][n4] = *(const float4*)&hbase[k * 16 + n4 * 4];
    __syncthreads();

    const float4 ng4 = *(const float4*)&ngw[ch4];

    // gate + correction + RMSNorm, register-resident per row
    #pragma unroll
    for (int i = 0; i < 8; ++i) {
        int row = i * 4 + (t >> 6);            // row owned entirely by this wave
        ushort4 yu = *(const ushort4*)&yb[(size_t)row * DINN + ch4];
        ushort4 zu = *(const ushort4*)&zb[(size_t)row * DINN + ch4];
        float4 yv = { bf2f(yu.x), bf2f(yu.y), bf2f(yu.z), bf2f(yu.w) };
        float4 zv = { bf2f(zu.x), bf2f(zu.y), bf2f(zu.z), bf2f(zu.w) };
        float4 C0 = *(const float4*)&Cs[row][0];
        float4 C1 = *(const float4*)&Cs[row][4];
        float4 C2 = *(const float4*)&Cs[row][8];
        float4 C3 = *(const float4*)&Cs[row][12];
        float cdv = cds[row][hh];
        float corr[4];
        #pragma unroll
        for (int k = 0; k < 4; ++k) {
            float s = H[k][0].x * C0.x + H[k][0].y * C0.y + H[k][0].z * C0.z + H[k][0].w * C0.w;
            s += H[k][1].x * C1.x + H[k][1].y * C1.y + H[k][1].z * C1.z + H[k][1].w * C1.w;
            s += H[k][2].x * C2.x + H[k][2].y * C2.y + H[k][2].z * C2.z + H[k][2].w * C2.w;
            s += H[k][3].x * C3.x + H[k][3].y * C3.y + H[k][3].z * C3.z + H[k][3].w * C3.w;
            corr[k] = s * cdv;
        }
        yv.x += corr[0]; yv.y += corr[1]; yv.z += corr[2]; yv.w += corr[3];
        float4 gv;
        gv.x = yv.x * zv.x / (1.f + expf(-zv.x));
        gv.y = yv.y * zv.y / (1.f + expf(-zv.y));
        gv.z = yv.z * zv.z / (1.f + expf(-zv.z));
        gv.w = yv.w * zv.w / (1.f + expf(-zv.w));
        // wave all-reduce of row sum-of-squares (64 lanes x 4 cols)
        float s = gv.x * gv.x + gv.y * gv.y + gv.z * gv.z + gv.w * gv.w;
        s += __shfl_xor(s, 1);  s += __shfl_xor(s, 2);  s += __shfl_xor(s, 4);
        s += __shfl_xor(s, 8);  s += __shfl_xor(s, 16); s += __shfl_xor(s, 32);
        float rs = rsqrtf(s * (1.f / 256.f) + EPSF);
        ushort4 o;
        o.x = f2bf(gv.x * rs * ng4.x);
        o.y = f2bf(gv.y * rs * ng4.y);
        o.z = f2bf(gv.z * rs * ng4.z);
        o.w = f2bf(gv.w * rs * ng4.w);
        *(ushort4*)&gb[row][ch4] = o;
    }
    __syncthreads();

    const int w = t >> 6, l = t & 63;
    const int j = l & 15, kb = (l >> 4) * 8;
    bf16x8 bf[8];
    #pragma unroll
    for (int ks = 0; ks < 8; ++ks)
        bf[ks] = *(const bf16x8*)&Wob[(size_t)(16 * w + j) * DINN + ks * 32 + kb];
    #pragma unroll
    for (int mt = 0; mt < 2; ++mt) {
        f32x4 acc = {0.f, 0.f, 0.f, 0.f};
        #pragma unroll
        for (int ks = 0; ks < 8; ++ks) {
            bf16x8 af = *(const bf16x8*)&gb[mt * 16 + j][ks * 32 + kb];
            acc = __builtin_amdgcn_mfma_f32_16x16x32_bf16(af, bf[ks], acc, 0, 0, 0);
        }
        #pragma unroll
        for (int r = 0; r < 4; ++r) {
            size_t row = (size_t)m0 + mt * 16 + (l >> 4) * 4 + r;
            size_t oidx = row * 64 + 16 * w + j;
            out[oidx] = acc[r] + 2.f * x[oidx];
        }
    }
}

extern "C" void kernel_launch(void* const* d_in, const int* in_sizes, int n_in,
                              void* d_out, int out_size, void* d_ws, size_t ws_size,
                              hipStream_t stream) {
    const float* x          = (const float*)d_in[0];
    const float* in_proj_w  = (const float*)d_in[1];
    const float* conv_w     = (const float*)d_in[2];
    const float* conv_b     = (const float*)d_in[3];
    const float* dt_bias    = (const float*)d_in[4];
    const float* A_log      = (const float*)d_in[5];
    const float* D          = (const float*)d_in[6];
    const float* norm_gate  = (const float*)d_in[7];
    const float* out_proj_w = (const float*)d_in[8];
    const float* block_norm = (const float*)d_in[9];
    float* out = (float*)d_out;

    float* h0b   = (float*)d_ws;                               //  2,097,152 f32
    float* cdec  = h0b  + (size_t)BB * NHEADS * NCH * 1024;    //    131,072 f32
    float* Cp    = cdec + (size_t)BB * NHEADS * LL;            //    524,288 f32
    float* dtb   = Cp   + (size_t)BB * LL * DSTATE;            //    131,072 f32
    ushort* ybf  = (ushort*)(dtb + (size_t)BB * NHEADS * LL);  //  8,388,608 us
    ushort* zbuf = ybf  + (size_t)BB * LL * DINN;              //  8,388,608 us
    ushort* xbc  = zbuf + (size_t)BB * LL * DINN;              //  9,437,184 us
    ushort* Wb   = xbc  + (size_t)BB * LL * 288;               //     35,072 us
    ushort* Wob  = Wb   + (size_t)DINPROJ * 64;                //     16,384 us

    kwcvt<<<201, 256, 0, stream>>>(in_proj_w, out_proj_w, Wb, Wob);
    k1_mfma<<<1024, 256, 0, stream>>>(x, Wb, block_norm, zbuf, xbc);
    kdt<<<512, 256, 0, stream>>>(x, in_proj_w, block_norm, dt_bias, dtb);
    k3a_ssd<<<2048, 256, 0, stream>>>(xbc, dtb, conv_w, conv_b, A_log, D, ybf, h0b, cdec, Cp);
    k3b_chunkscan<<<128, 256, 0, stream>>>(h0b, cdec);
    k4_out<<<1024, 256, 0, stream>>>(ybf, zbuf, norm_gate, Wob, x, h0b, cdec, Cp, out);
}

// Round 9
// 87.010 us; speedup vs baseline: 1.2932x; 1.0440x over previous
//
#include <hip/hip_runtime.h>
#include <math.h>

#define BB 32
#define LL 1024
#define DIMM 64
#define DINN 256
#define NHEADS 4
#define DSTATE 16
#define DINPROJ 548
#define EPSF 1e-5f
#define NCH 16    // chunks per sequence
#define CS 64     // chunk size

typedef __attribute__((ext_vector_type(8))) short bf16x8;
typedef __attribute__((ext_vector_type(4))) float f32x4;

__device__ inline ushort f2bf(float f) {
    union { float f; unsigned u; } v; v.f = f;
    unsigned r = (v.u + 0x7FFFu + ((v.u >> 16) & 1u)) >> 16;
    return (ushort)r;
}
__device__ inline float bf2f(ushort u) {
    union { float f; unsigned u; } v; v.u = ((unsigned)u) << 16; return v.f;
}

// ---------------- K0: convert weights to bf16 ----------------
__global__ __launch_bounds__(256) void kwcvt(
        const float* __restrict__ Win, const float* __restrict__ Wout,
        ushort* __restrict__ Wb, ushort* __restrict__ Wob) {
    int i = blockIdx.x * 256 + threadIdx.x;
    if (i < DINPROJ * 64) Wb[i] = f2bf(Win[i]);
    else if (i < DINPROJ * 64 + 64 * DINN) {
        int j = i - DINPROJ * 64;
        Wob[j] = f2bf(Wout[j]);
    }
}

// ------- K1: RMSNorm + in_proj (bf16 MFMA) + fp32 dt + coalesced stores -------
// grid 1024 (M-tile 32), block 256 = 4 waves
__global__ __launch_bounds__(256) void k1_mfma(
        const float* __restrict__ x, const ushort* __restrict__ Wb,
        const float* __restrict__ bnw, const float* __restrict__ Wfp,
        const float* __restrict__ dt_bias,
        ushort* __restrict__ zbuf, ushort* __restrict__ xbcbuf,
        float* __restrict__ dtbuf) {
    __shared__ __align__(16) union {
        struct { float u[32][68]; float wdt[4][68]; } a;   // 9.8 KB
        ushort ob[32][552];                                 // 35.3 KB
    } s;
    __shared__ float rstd[32];
    const int t = threadIdx.x;
    const int m0 = blockIdx.x * 32;
    const int b = m0 >> 10;
    const int lbase = m0 & 1023;

    const float* xrow = x + (size_t)m0 * 64;
    #pragma unroll
    for (int i = 0; i < 2; ++i) {
        int idx = t + i * 256;
        float4 v = ((const float4*)xrow)[idx];
        *(float4*)&s.a.u[idx >> 4][(idx & 15) * 4] = v;
    }
    s.a.wdt[t >> 6][t & 63] = Wfp[(size_t)(544 + (t >> 6)) * 64 + (t & 63)] * bnw[t & 63];
    __syncthreads();
    {
        int row = t >> 3, part = t & 7;
        float ss = 0.f;
        #pragma unroll
        for (int j = 0; j < 8; ++j) { float v = s.a.u[row][part * 8 + j]; ss = fmaf(v, v, ss); }
        ss += __shfl_xor(ss, 1); ss += __shfl_xor(ss, 2); ss += __shfl_xor(ss, 4);
        if (part == 0) rstd[row] = rsqrtf(ss * (1.f / 64.f) + EPSF);
    }
    __syncthreads();

    const int w = t >> 6, l = t & 63;
    const int a = l & 15, kb = (l >> 4) * 8;

    float4 bw[2][2];
    bw[0][0] = *(const float4*)&bnw[kb];
    bw[0][1] = *(const float4*)&bnw[kb + 4];
    bw[1][0] = *(const float4*)&bnw[32 + kb];
    bw[1][1] = *(const float4*)&bnw[32 + kb + 4];

    bf16x8 af[2][2];
    #pragma unroll
    for (int mt = 0; mt < 2; ++mt) {
        float rs = rstd[mt * 16 + a];
        #pragma unroll
        for (int kk = 0; kk < 2; ++kk) {
            float4 v0 = *(const float4*)&s.a.u[mt * 16 + a][kk * 32 + kb];
            float4 v1 = *(const float4*)&s.a.u[mt * 16 + a][kk * 32 + kb + 4];
            ushort* p = (ushort*)&af[mt][kk];
            p[0] = f2bf(v0.x * rs * bw[kk][0].x);
            p[1] = f2bf(v0.y * rs * bw[kk][0].y);
            p[2] = f2bf(v0.z * rs * bw[kk][0].z);
            p[3] = f2bf(v0.w * rs * bw[kk][0].w);
            p[4] = f2bf(v1.x * rs * bw[kk][1].x);
            p[5] = f2bf(v1.y * rs * bw[kk][1].y);
            p[6] = f2bf(v1.z * rs * bw[kk][1].z);
            p[7] = f2bf(v1.w * rs * bw[kk][1].w);
        }
    }

    // fp32 dt for this block's 32 rows (128 threads: row = t>>2, h = t&3)
    if (t < 128) {
        int row = t >> 2, h = t & 3;
        const float* ur = s.a.u[row];
        const float* wr = s.a.wdt[h];
        float sd = 0.f;
        #pragma unroll
        for (int k4 = 0; k4 < 16; ++k4) {
            float4 uv = *(const float4*)&ur[k4 * 4];
            float4 wv = *(const float4*)&wr[k4 * 4];
            sd = fmaf(uv.x, wv.x, sd); sd = fmaf(uv.y, wv.y, sd);
            sd = fmaf(uv.z, wv.z, sd); sd = fmaf(uv.w, wv.w, sd);
        }
        sd = sd * rstd[row] + dt_bias[h];
        sd = fmaxf(sd, 0.f) + log1pf(expf(-fabsf(sd)));
        dtbuf[((size_t)(b * 4 + h)) * LL + lbase + row] = sd;
    }
    __syncthreads();   // u/wdt dead; ob may now be written

    for (int nt = w; nt < 34; nt += 4) {
        const ushort* wbp = Wb + (size_t)(nt * 16 + a) * 64 + kb;
        bf16x8 b0 = *(const bf16x8*)wbp;
        bf16x8 b1 = *(const bf16x8*)(wbp + 32);
        #pragma unroll
        for (int mt = 0; mt < 2; ++mt) {
            f32x4 acc = {0.f, 0.f, 0.f, 0.f};
            acc = __builtin_amdgcn_mfma_f32_16x16x32_bf16(af[mt][0], b0, acc, 0, 0, 0);
            acc = __builtin_amdgcn_mfma_f32_16x16x32_bf16(af[mt][1], b1, acc, 0, 0, 0);
            int row0 = mt * 16 + (l >> 4) * 4;
            int col = nt * 16 + a;
            #pragma unroll
            for (int r = 0; r < 4; ++r) s.ob[row0 + r][col] = f2bf(acc[r]);
        }
    }
    __syncthreads();

    // coalesced stores: zbuf rows (512B) then xbc rows (576B)
    for (int i = t; i < 1024; i += 256) {           // 32 rows x 32 chunks
        int row = i >> 5, c8 = (i & 31) * 8;
        *(uint4*)&zbuf[(size_t)(m0 + row) * DINN + c8] = *(const uint4*)&s.ob[row][c8];
    }
    for (int i = t; i < 1152; i += 256) {           // 32 rows x 36 chunks
        int row = i / 36, c8 = (i % 36) * 8;
        *(uint4*)&xbcbuf[(size_t)(m0 + row) * 288 + c8] = *(const uint4*)&s.ob[row][256 + c8];
    }
}

// ---------------- K3a: SSD chunked scan via MFMA (bf16 in/out) ----------------
// grid 2048 = (b,h,c); block 256 = 4 waves
__global__ __launch_bounds__(256) void k3a_ssd(
        const ushort* __restrict__ xbcbuf, const float* __restrict__ dtbuf,
        const float* __restrict__ conv_w, const float* __restrict__ conv_b,
        const float* __restrict__ A_log, const float* __restrict__ Dp,
        ushort* __restrict__ y, float* __restrict__ h0buf,
        float* __restrict__ cdecbuf, float* __restrict__ Cpost) {
    const int bid = blockIdx.x;
    const int c = bid & 15, h = (bid >> 4) & 3, b = bid >> 6;
    const int t = threadIdx.x;

    __shared__ __align__(16) union {
        struct { ushort rawx[67][64]; ushort rawbc[67][32]; } st;  // 12.9 KB
        struct { ushort Mb[64][72]; ushort BwT[16][72]; } ssd;     // 11.5 KB
    } uu;
    __shared__ ushort XbT[64][72];   // x transposed [chan][token], bf16
    __shared__ ushort Bb[64][40];    // [token][state(16) pad->40]
    __shared__ ushort Cb[64][40];
    __shared__ float dtt[64], laa[64], ww[64];

    const float A  = -expf(A_log[h]);
    const float Dh = Dp[h];
    const int l0 = c * CS;
    const ushort* xb = xbcbuf + (size_t)b * LL * 288;   // per-batch base

    // ---- phase 1: stage raw (bf16) + zero pads + dt/la scan ----
    for (int i = t; i < 67 * 32; i += 256) {
        int r = i >> 5, cu = i & 31;
        int l = l0 - 3 + r;
        ((uint*)&uu.st.rawx[r][0])[cu] =
            (l >= 0) ? ((const uint*)(xb + (size_t)l * 288 + h * 64))[cu] : 0u;
    }
    for (int i = t; i < 67 * 16; i += 256) {
        int r = i >> 4, cu = i & 15;
        int l = l0 - 3 + r;
        ((uint*)&uu.st.rawbc[r][0])[cu] =
            (l >= 0) ? ((const uint*)(xb + (size_t)l * 288 + 256))[cu] : 0u;
    }
    {
        uint* pz = (uint*)&Bb[0][0];
        for (int i = t; i < 64 * 40 / 2; i += 256) pz[i] = 0;
        uint* pz2 = (uint*)&Cb[0][0];
        for (int i = t; i < 64 * 40 / 2; i += 256) pz2[i] = 0;
    }
    if (t < 64) {
        float dv = dtbuf[((size_t)(b * 4 + h)) * LL + l0 + t];  // softplus'ed dt
        float run = dv * A;
        #pragma unroll
        for (int off = 1; off < 64; off <<= 1) {
            float o = __shfl_up(run, off, 64);
            if (t >= off) run += o;
        }
        dtt[t] = dv;
        laa[t] = run;
        cdecbuf[((size_t)(b * 4 + h)) * LL + l0 + t] = expf(run);
        float laEnd = __shfl(run, 63, 64);
        ww[t] = dv * expf(laEnd - run);
    }
    __syncthreads();

    // ---- phase 2: conv + SiLU -> bf16 tiles ----
    {
        const int jx = t & 63;
        const int cx = h * 64 + jx;
        const float4 cwx = *(const float4*)&conv_w[cx * 4];
        const float  cbx = conv_b[cx];
        #pragma unroll
        for (int i = 0; i < 16; ++i) {
            int ss = (t >> 6) + i * 4;
            float v = cbx + bf2f(uu.st.rawx[ss][jx]) * cwx.x
                          + bf2f(uu.st.rawx[ss + 1][jx]) * cwx.y
                          + bf2f(uu.st.rawx[ss + 2][jx]) * cwx.z
                          + bf2f(uu.st.rawx[ss + 3][jx]) * cwx.w;
            v = v / (1.f + expf(-v));
            XbT[jx][ss] = f2bf(v);
        }
        const int jbc = t & 31, cbc = 256 + jbc;
        const float4 cwb = *(const float4*)&conv_w[cbc * 4];
        const float  cbb = conv_b[cbc];
        #pragma unroll
        for (int i = 0; i < 8; ++i) {
            int ss = (t >> 5) + i * 8;
            float v = cbb + bf2f(uu.st.rawbc[ss][jbc]) * cwb.x
                          + bf2f(uu.st.rawbc[ss + 1][jbc]) * cwb.y
                          + bf2f(uu.st.rawbc[ss + 2][jbc]) * cwb.z
                          + bf2f(uu.st.rawbc[ss + 3][jbc]) * cwb.w;
            v = v / (1.f + expf(-v));
            if (jbc < 16) Bb[ss][jbc] = f2bf(v);
            else {
                Cb[ss][jbc - 16] = f2bf(v);
                Cpost[((size_t)b * LL + l0 + ss) * DSTATE + (jbc - 16)] = v;
            }
        }
    }
    __syncthreads();

    const int w = t >> 6, l = t & 63;
    const int fr = l & 15, fq = l >> 4;

    // ---- phase 3: G = C.B^T (K=32 padded), mask -> Mb; fill BwT ----
    f32x4 gacc[4];
    {
        bf16x8 ca = *(const bf16x8*)&Cb[w * 16 + fr][fq * 8];
        #pragma unroll
        for (int jt = 0; jt < 4; ++jt) {
            bf16x8 bb = *(const bf16x8*)&Bb[jt * 16 + fr][fq * 8];
            f32x4 z = {0.f, 0.f, 0.f, 0.f};
            gacc[jt] = __builtin_amdgcn_mfma_f32_16x16x32_bf16(ca, bb, z, 0, 0, 0);
        }
    }
    #pragma unroll
    for (int jt = 0; jt < 4; ++jt) {
        int j = jt * 16 + fr;
        float laj = laa[j], dtj = dtt[j];
        #pragma unroll
        for (int r = 0; r < 4; ++r) {
            int i = w * 16 + fq * 4 + r;
            float m = (j <= i) ? gacc[jt][r] * expf(laa[i] - laj) * dtj : 0.f;
            uu.ssd.Mb[i][j] = f2bf(m);
        }
    }
    #pragma unroll
    for (int i2 = 0; i2 < 4; ++i2) {
        int idx = t + i2 * 256;
        int n = idx & 15, jj = idx >> 4;
        uu.ssd.BwT[n][jj] = f2bf(ww[jj] * bf2f(Bb[jj][n]));
    }
    __syncthreads();

    // ---- phase 4: Y = M.X (+D skip) written back into Mb rows; S = X^T.(wB) ----
    {
        bf16x8 ma0 = *(const bf16x8*)&uu.ssd.Mb[w * 16 + fr][fq * 8];
        bf16x8 ma1 = *(const bf16x8*)&uu.ssd.Mb[w * 16 + fr][32 + fq * 8];
        #pragma unroll
        for (int pt = 0; pt < 4; ++pt) {
            bf16x8 xb0 = *(const bf16x8*)&XbT[pt * 16 + fr][fq * 8];
            bf16x8 xb1 = *(const bf16x8*)&XbT[pt * 16 + fr][32 + fq * 8];
            f32x4 acc = {0.f, 0.f, 0.f, 0.f};
            acc = __builtin_amdgcn_mfma_f32_16x16x32_bf16(ma0, xb0, acc, 0, 0, 0);
            acc = __builtin_amdgcn_mfma_f32_16x16x32_bf16(ma1, xb1, acc, 0, 0, 0);
            #pragma unroll
            for (int r = 0; r < 4; ++r) {
                int i = w * 16 + fq * 4 + r;          // this wave's own rows
                int p = pt * 16 + fr;
                float xv = bf2f(XbT[p][i]);
                uu.ssd.Mb[i][p] = f2bf(acc[r] + Dh * xv);
            }
        }
    }
    if (c < 15) {
        bf16x8 xa0 = *(const bf16x8*)&XbT[w * 16 + fr][fq * 8];
        bf16x8 xa1 = *(const bf16x8*)&XbT[w * 16 + fr][32 + fq * 8];
        bf16x8 bw0 = *(const bf16x8*)&uu.ssd.BwT[fr][fq * 8];
        bf16x8 bw1 = *(const bf16x8*)&uu.ssd.BwT[fr][32 + fq * 8];
        f32x4 acc = {0.f, 0.f, 0.f, 0.f};
        acc = __builtin_amdgcn_mfma_f32_16x16x32_bf16(xa0, bw0, acc, 0, 0, 0);
        acc = __builtin_amdgcn_mfma_f32_16x16x32_bf16(xa1, bw1, acc, 0, 0, 0);
        float* Sdst = h0buf + (((size_t)(b * 4 + h)) * NCH + (c + 1)) * 1024;
        #pragma unroll
        for (int r = 0; r < 4; ++r) {
            int p = w * 16 + fq * 4 + r;
            Sdst[p * 16 + fr] = acc[r];
        }
    }
    __syncthreads();

    // coalesced y store: 64 rows x 128B segments
    {
        ushort* ybase = y + ((size_t)b * LL + l0) * DINN + h * 64;
        #pragma unroll
        for (int ii = 0; ii < 2; ++ii) {
            int idx = t + ii * 256;
            int row = idx >> 3, c8 = (idx & 7) * 8;
            *(uint4*)&ybase[(size_t)row * DINN + c8] = *(const uint4*)&uu.ssd.Mb[row][c8];
        }
    }
}

// ---------------- K3b: chunk-level scan (16 chunks) ----------------
__global__ __launch_bounds__(256) void k3b_chunkscan(
        float* __restrict__ h0buf, const float* __restrict__ cdecbuf) {
    const int bh = blockIdx.x;
    const int t = threadIdx.x;
    float* base = h0buf + (size_t)bh * NCH * 1024;
    const float* cd = cdecbuf + (size_t)bh * LL;
    float4 run = {0.f, 0.f, 0.f, 0.f};
    *(float4*)&base[(size_t)t * 4] = run;
    #pragma unroll
    for (int c = 1; c < NCH; ++c) {
        float P = cd[c * CS - 1];
        float4 S = *(float4*)&base[(size_t)c * 1024 + t * 4];
        run.x = fmaf(run.x, P, S.x);
        run.y = fmaf(run.y, P, S.y);
        run.z = fmaf(run.z, P, S.z);
        run.w = fmaf(run.w, P, S.w);
        *(float4*)&base[(size_t)c * 1024 + t * 4] = run;
    }
}

// ------- K4: correction (H from global) + gate + RMSNorm + out_proj -------
__global__ __launch_bounds__(256) void k4_out(
        const ushort* __restrict__ ybf, const ushort* __restrict__ zbuf,
        const float* __restrict__ ngw, const ushort* __restrict__ Wob,
        const float* __restrict__ x, const float* __restrict__ h0buf,
        const float* __restrict__ cdecbuf, const float* __restrict__ Cpost,
        float* __restrict__ out) {
    __shared__ float Cs[32][16];
    __shared__ float cds[32][4];
    __shared__ ushort gb[32][264];      // 16.9 KB
    const int t = threadIdx.x;
    const int m0 = blockIdx.x * 32;
    const int b  = m0 >> 10;
    const int l0 = m0 & 1023;
    const int ck = l0 >> 6;
    const ushort* yb = ybf + (size_t)m0 * DINN;
    const ushort* zb = zbuf + (size_t)m0 * DINN;

    if (t < 128) {
        int r = t >> 2, n0 = (t & 3) * 4;
        *(float4*)&Cs[r][n0] = *(const float4*)&Cpost[((size_t)b * LL + l0 + r) * DSTATE + n0];
    } else {
        int tt = t - 128;
        int r = tt >> 2, hh = tt & 3;
        cds[r][hh] = cdecbuf[((size_t)(b * 4 + hh)) * LL + l0 + r];
    }

    const int ch4 = (t & 63) * 4;
    const int hh  = ch4 >> 6;
    const int p0  = ch4 & 63;
    const float* hbase = h0buf + (((size_t)(b * 4 + hh)) * NCH + ck) * 1024 + p0 * 16;
    float4 H[4][4];
    #pragma unroll
    for (int k = 0; k < 4; ++k)
        #pragma unroll
        for (int n4 = 0; n4 < 4; ++n4)
            H[k][n4] = *(const float4*)&hbase[k * 16 + n4 * 4];
    __syncthreads();

    const float4 ng4 = *(const float4*)&ngw[ch4];

    #pragma unroll
    for (int i = 0; i < 8; ++i) {
        int row = i * 4 + (t >> 6);
        ushort4 yu = *(const ushort4*)&yb[(size_t)row * DINN + ch4];
        ushort4 zu = *(const ushort4*)&zb[(size_t)row * DINN + ch4];
        float4 yv = { bf2f(yu.x), bf2f(yu.y), bf2f(yu.z), bf2f(yu.w) };
        float4 zv = { bf2f(zu.x), bf2f(zu.y), bf2f(zu.z), bf2f(zu.w) };
        float4 C0 = *(const float4*)&Cs[row][0];
        float4 C1 = *(const float4*)&Cs[row][4];
        float4 C2 = *(const float4*)&Cs[row][8];
        float4 C3 = *(const float4*)&Cs[row][12];
        float cdv = cds[row][hh];
        float corr[4];
        #pragma unroll
        for (int k = 0; k < 4; ++k) {
            float s = H[k][0].x * C0.x + H[k][0].y * C0.y + H[k][0].z * C0.z + H[k][0].w * C0.w;
            s += H[k][1].x * C1.x + H[k][1].y * C1.y + H[k][1].z * C1.z + H[k][1].w * C1.w;
            s += H[k][2].x * C2.x + H[k][2].y * C2.y + H[k][2].z * C2.z + H[k][2].w * C2.w;
            s += H[k][3].x * C3.x + H[k][3].y * C3.y + H[k][3].z * C3.z + H[k][3].w * C3.w;
            corr[k] = s * cdv;
        }
        yv.x += corr[0]; yv.y += corr[1]; yv.z += corr[2]; yv.w += corr[3];
        float4 gv;
        gv.x = yv.x * zv.x / (1.f + expf(-zv.x));
        gv.y = yv.y * zv.y / (1.f + expf(-zv.y));
        gv.z = yv.z * zv.z / (1.f + expf(-zv.z));
        gv.w = yv.w * zv.w / (1.f + expf(-zv.w));
        float s = gv.x * gv.x + gv.y * gv.y + gv.z * gv.z + gv.w * gv.w;
        s += __shfl_xor(s, 1);  s += __shfl_xor(s, 2);  s += __shfl_xor(s, 4);
        s += __shfl_xor(s, 8);  s += __shfl_xor(s, 16); s += __shfl_xor(s, 32);
        float rs = rsqrtf(s * (1.f / 256.f) + EPSF);
        ushort4 o;
        o.x = f2bf(gv.x * rs * ng4.x);
        o.y = f2bf(gv.y * rs * ng4.y);
        o.z = f2bf(gv.z * rs * ng4.z);
        o.w = f2bf(gv.w * rs * ng4.w);
        *(ushort4*)&gb[row][ch4] = o;
    }
    __syncthreads();

    const int w = t >> 6, l = t & 63;
    const int j = l & 15, kb = (l >> 4) * 8;
    bf16x8 bf[8];
    #pragma unroll
    for (int ks = 0; ks < 8; ++ks)
        bf[ks] = *(const bf16x8*)&Wob[(size_t)(16 * w + j) * DINN + ks * 32 + kb];
    #pragma unroll
    for (int mt = 0; mt < 2; ++mt) {
        f32x4 acc = {0.f, 0.f, 0.f, 0.f};
        #pragma unroll
        for (int ks = 0; ks < 8; ++ks) {
            bf16x8 af = *(const bf16x8*)&gb[mt * 16 + j][ks * 32 + kb];
            acc = __builtin_amdgcn_mfma_f32_16x16x32_bf16(af, bf[ks], acc, 0, 0, 0);
        }
        #pragma unroll
        for (int r = 0; r < 4; ++r) {
            size_t row = (size_t)m0 + mt * 16 + (l >> 4) * 4 + r;
            size_t oidx = row * 64 + 16 * w + j;
            out[oidx] = acc[r] + 2.f * x[oidx];
        }
    }
}

extern "C" void kernel_launch(void* const* d_in, const int* in_sizes, int n_in,
                              void* d_out, int out_size, void* d_ws, size_t ws_size,
                              hipStream_t stream) {
    const float* x          = (const float*)d_in[0];
    const float* in_proj_w  = (const float*)d_in[1];
    const float* conv_w     = (const float*)d_in[2];
    const float* conv_b     = (const float*)d_in[3];
    const float* dt_bias    = (const float*)d_in[4];
    const float* A_log      = (const float*)d_in[5];
    const float* D          = (const float*)d_in[6];
    const float* norm_gate  = (const float*)d_in[7];
    const float* out_proj_w = (const float*)d_in[8];
    const float* block_norm = (const float*)d_in[9];
    float* out = (float*)d_out;

    float* h0b   = (float*)d_ws;                               //  2,097,152 f32
    float* cdec  = h0b  + (size_t)BB * NHEADS * NCH * 1024;    //    131,072 f32
    float* Cp    = cdec + (size_t)BB * NHEADS * LL;            //    524,288 f32
    float* dtb   = Cp   + (size_t)BB * LL * DSTATE;            //    131,072 f32
    ushort* ybf  = (ushort*)(dtb + (size_t)BB * NHEADS * LL);  //  8,388,608 us
    ushort* zbuf = ybf  + (size_t)BB * LL * DINN;              //  8,388,608 us
    ushort* xbc  = zbuf + (size_t)BB * LL * DINN;              //  9,437,184 us
    ushort* Wb   = xbc  + (size_t)BB * LL * 288;               //     35,072 us
    ushort* Wob  = Wb   + (size_t)DINPROJ * 64;                //     16,384 us

    kwcvt<<<201, 256, 0, stream>>>(in_proj_w, out_proj_w, Wb, Wob);
    k1_mfma<<<1024, 256, 0, stream>>>(x, Wb, block_norm, in_proj_w, dt_bias, zbuf, xbc, dtb);
    k3a_ssd<<<2048, 256, 0, stream>>>(xbc, dtb, conv_w, conv_b, A_log, D, ybf, h0b, cdec, Cp);
    k3b_chunkscan<<<128, 256, 0, stream>>>(h0b, cdec);
    k4_out<<<1024, 256, 0, stream>>>(ybf, zbuf, norm_gate, Wob, x, h0b, cdec, Cp, out);
}

// Round 10
// 77.939 us; speedup vs baseline: 1.4437x; 1.1164x over previous
//
#include <hip/hip_runtime.h>
#include <math.h>

#define BB 32
#define LL 1024
#define DIMM 64
#define DINN 256
#define NHEADS 4
#define DSTATE 16
#define DINPROJ 548
#define EPSF 1e-5f
#define NCH 16    // chunks per sequence
#define CS 64     // chunk size

typedef __attribute__((ext_vector_type(8))) short bf16x8;
typedef __attribute__((ext_vector_type(4))) float f32x4;

__device__ inline ushort f2bf(float f) {
    union { float f; unsigned u; } v; v.f = f;
    unsigned r = (v.u + 0x7FFFu + ((v.u >> 16) & 1u)) >> 16;
    return (ushort)r;
}
__device__ inline float bf2f(ushort u) {
    union { float f; unsigned u; } v; v.u = ((unsigned)u) << 16; return v.f;
}
__device__ inline float fexp(float v) { return __expf(v); }               // v_exp_f32 path
__device__ inline float fsilu(float v) {
    return v * __builtin_amdgcn_rcpf(1.f + __expf(-v));                   // ~4 instrs
}

// ---------------- K0: convert weights to bf16 ----------------
__global__ __launch_bounds__(256) void kwcvt(
        const float* __restrict__ Win, const float* __restrict__ Wout,
        ushort* __restrict__ Wb, ushort* __restrict__ Wob) {
    int i = blockIdx.x * 256 + threadIdx.x;
    if (i < DINPROJ * 64) Wb[i] = f2bf(Win[i]);
    else if (i < DINPROJ * 64 + 64 * DINN) {
        int j = i - DINPROJ * 64;
        Wob[j] = f2bf(Wout[j]);
    }
}

// -- K1: RMSNorm + in_proj (bf16 MFMA) + fp32 dt + silu(z) + coalesced stores --
// grid 1024 (M-tile 32), block 256 = 4 waves
__global__ __launch_bounds__(256) void k1_mfma(
        const float* __restrict__ x, const ushort* __restrict__ Wb,
        const float* __restrict__ bnw, const float* __restrict__ Wfp,
        const float* __restrict__ dt_bias,
        ushort* __restrict__ zbuf, ushort* __restrict__ xbcbuf,
        float* __restrict__ dtbuf) {
    __shared__ __align__(16) union {
        struct { float u[32][68]; float wdt[4][68]; } a;   // 9.8 KB
        ushort ob[32][552];                                 // 35.3 KB
    } s;
    __shared__ float rstd[32];
    const int t = threadIdx.x;
    const int m0 = blockIdx.x * 32;
    const int b = m0 >> 10;
    const int lbase = m0 & 1023;

    const float* xrow = x + (size_t)m0 * 64;
    #pragma unroll
    for (int i = 0; i < 2; ++i) {
        int idx = t + i * 256;
        float4 v = ((const float4*)xrow)[idx];
        *(float4*)&s.a.u[idx >> 4][(idx & 15) * 4] = v;
    }
    s.a.wdt[t >> 6][t & 63] = Wfp[(size_t)(544 + (t >> 6)) * 64 + (t & 63)] * bnw[t & 63];
    __syncthreads();
    {
        int row = t >> 3, part = t & 7;
        float ss = 0.f;
        #pragma unroll
        for (int j = 0; j < 8; ++j) { float v = s.a.u[row][part * 8 + j]; ss = fmaf(v, v, ss); }
        ss += __shfl_xor(ss, 1); ss += __shfl_xor(ss, 2); ss += __shfl_xor(ss, 4);
        if (part == 0) rstd[row] = rsqrtf(ss * (1.f / 64.f) + EPSF);
    }
    __syncthreads();

    const int w = t >> 6, l = t & 63;
    const int a = l & 15, kb = (l >> 4) * 8;

    float4 bw[2][2];
    bw[0][0] = *(const float4*)&bnw[kb];
    bw[0][1] = *(const float4*)&bnw[kb + 4];
    bw[1][0] = *(const float4*)&bnw[32 + kb];
    bw[1][1] = *(const float4*)&bnw[32 + kb + 4];

    bf16x8 af[2][2];
    #pragma unroll
    for (int mt = 0; mt < 2; ++mt) {
        float rs = rstd[mt * 16 + a];
        #pragma unroll
        for (int kk = 0; kk < 2; ++kk) {
            float4 v0 = *(const float4*)&s.a.u[mt * 16 + a][kk * 32 + kb];
            float4 v1 = *(const float4*)&s.a.u[mt * 16 + a][kk * 32 + kb + 4];
            ushort* p = (ushort*)&af[mt][kk];
            p[0] = f2bf(v0.x * rs * bw[kk][0].x);
            p[1] = f2bf(v0.y * rs * bw[kk][0].y);
            p[2] = f2bf(v0.z * rs * bw[kk][0].z);
            p[3] = f2bf(v0.w * rs * bw[kk][0].w);
            p[4] = f2bf(v1.x * rs * bw[kk][1].x);
            p[5] = f2bf(v1.y * rs * bw[kk][1].y);
            p[6] = f2bf(v1.z * rs * bw[kk][1].z);
            p[7] = f2bf(v1.w * rs * bw[kk][1].w);
        }
    }

    // fp32 dt for this block's 32 rows (128 threads: row = t>>2, h = t&3)
    if (t < 128) {
        int row = t >> 2, h = t & 3;
        const float* ur = s.a.u[row];
        const float* wr = s.a.wdt[h];
        float sd = 0.f;
        #pragma unroll
        for (int k4 = 0; k4 < 16; ++k4) {
            float4 uv = *(const float4*)&ur[k4 * 4];
            float4 wv = *(const float4*)&wr[k4 * 4];
            sd = fmaf(uv.x, wv.x, sd); sd = fmaf(uv.y, wv.y, sd);
            sd = fmaf(uv.z, wv.z, sd); sd = fmaf(uv.w, wv.w, sd);
        }
        sd = sd * rstd[row] + dt_bias[h];
        sd = fmaxf(sd, 0.f) + log1pf(expf(-fabsf(sd)));   // keep precise
        dtbuf[((size_t)(b * 4 + h)) * LL + lbase + row] = sd;
    }
    __syncthreads();   // u/wdt dead; ob may now be written

    for (int nt = w; nt < 34; nt += 4) {
        const ushort* wbp = Wb + (size_t)(nt * 16 + a) * 64 + kb;
        bf16x8 b0 = *(const bf16x8*)wbp;
        bf16x8 b1 = *(const bf16x8*)(wbp + 32);
        #pragma unroll
        for (int mt = 0; mt < 2; ++mt) {
            f32x4 acc = {0.f, 0.f, 0.f, 0.f};
            acc = __builtin_amdgcn_mfma_f32_16x16x32_bf16(af[mt][0], b0, acc, 0, 0, 0);
            acc = __builtin_amdgcn_mfma_f32_16x16x32_bf16(af[mt][1], b1, acc, 0, 0, 0);
            int row0 = mt * 16 + (l >> 4) * 4;
            int col = nt * 16 + a;
            if (nt < 16) {   // z columns: store silu(z) directly
                #pragma unroll
                for (int r = 0; r < 4; ++r) s.ob[row0 + r][col] = f2bf(fsilu(acc[r]));
            } else {
                #pragma unroll
                for (int r = 0; r < 4; ++r) s.ob[row0 + r][col] = f2bf(acc[r]);
            }
        }
    }
    __syncthreads();

    // coalesced stores: zbuf rows (512B) then xbc rows (576B)
    for (int i = t; i < 1024; i += 256) {           // 32 rows x 32 chunks
        int row = i >> 5, c8 = (i & 31) * 8;
        *(uint4*)&zbuf[(size_t)(m0 + row) * DINN + c8] = *(const uint4*)&s.ob[row][c8];
    }
    for (int i = t; i < 1152; i += 256) {           // 32 rows x 36 chunks
        int row = i / 36, c8 = (i % 36) * 8;
        *(uint4*)&xbcbuf[(size_t)(m0 + row) * 288 + c8] = *(const uint4*)&s.ob[row][256 + c8];
    }
}

// ---------------- K3a: SSD chunked scan via MFMA (bf16 in/out) ----------------
// grid 2048 = (b,h,c); block 256 = 4 waves
__global__ __launch_bounds__(256) void k3a_ssd(
        const ushort* __restrict__ xbcbuf, const float* __restrict__ dtbuf,
        const float* __restrict__ conv_w, const float* __restrict__ conv_b,
        const float* __restrict__ A_log, const float* __restrict__ Dp,
        ushort* __restrict__ y, float* __restrict__ h0buf,
        float* __restrict__ cdecbuf, float* __restrict__ Cpost) {
    const int bid = blockIdx.x;
    const int c = bid & 15, h = (bid >> 4) & 3, b = bid >> 6;
    const int t = threadIdx.x;

    __shared__ __align__(16) union {
        struct { ushort rawx[67][64]; ushort rawbc[67][32]; } st;  // 12.9 KB
        struct { ushort Mb[64][72]; ushort BwT[16][72]; } ssd;     // 11.5 KB
    } uu;
    __shared__ ushort XbT[64][72];   // x transposed [chan][token], bf16
    __shared__ ushort Bb[64][40];    // [token][state(16) pad->40]
    __shared__ ushort Cb[64][40];
    __shared__ float dtt[64], laa[64], ww[64];

    const float A  = -expf(A_log[h]);
    const float Dh = Dp[h];
    const int l0 = c * CS;
    const ushort* xb = xbcbuf + (size_t)b * LL * 288;   // per-batch base

    // ---- phase 1: stage raw (bf16) + zero pads + dt/la scan ----
    for (int i = t; i < 67 * 32; i += 256) {
        int r = i >> 5, cu = i & 31;
        int l = l0 - 3 + r;
        ((uint*)&uu.st.rawx[r][0])[cu] =
            (l >= 0) ? ((const uint*)(xb + (size_t)l * 288 + h * 64))[cu] : 0u;
    }
    for (int i = t; i < 67 * 16; i += 256) {
        int r = i >> 4, cu = i & 15;
        int l = l0 - 3 + r;
        ((uint*)&uu.st.rawbc[r][0])[cu] =
            (l >= 0) ? ((const uint*)(xb + (size_t)l * 288 + 256))[cu] : 0u;
    }
    {
        uint* pz = (uint*)&Bb[0][0];
        for (int i = t; i < 64 * 40 / 2; i += 256) pz[i] = 0;
        uint* pz2 = (uint*)&Cb[0][0];
        for (int i = t; i < 64 * 40 / 2; i += 256) pz2[i] = 0;
    }
    if (t < 64) {
        float dv = dtbuf[((size_t)(b * 4 + h)) * LL + l0 + t];  // softplus'ed dt
        float run = dv * A;
        #pragma unroll
        for (int off = 1; off < 64; off <<= 1) {
            float o = __shfl_up(run, off, 64);
            if (t >= off) run += o;
        }
        dtt[t] = dv;
        laa[t] = run;
        cdecbuf[((size_t)(b * 4 + h)) * LL + l0 + t] = fexp(run);
        float laEnd = __shfl(run, 63, 64);
        ww[t] = dv * fexp(laEnd - run);
    }
    __syncthreads();

    // ---- phase 2: conv + SiLU -> bf16 tiles ----
    {
        const int jx = t & 63;
        const int cx = h * 64 + jx;
        const float4 cwx = *(const float4*)&conv_w[cx * 4];
        const float  cbx = conv_b[cx];
        #pragma unroll
        for (int i = 0; i < 16; ++i) {
            int ss = (t >> 6) + i * 4;
            float v = cbx + bf2f(uu.st.rawx[ss][jx]) * cwx.x
                          + bf2f(uu.st.rawx[ss + 1][jx]) * cwx.y
                          + bf2f(uu.st.rawx[ss + 2][jx]) * cwx.z
                          + bf2f(uu.st.rawx[ss + 3][jx]) * cwx.w;
            XbT[jx][ss] = f2bf(fsilu(v));
        }
        const int jbc = t & 31, cbc = 256 + jbc;
        const float4 cwb = *(const float4*)&conv_w[cbc * 4];
        const float  cbb = conv_b[cbc];
        #pragma unroll
        for (int i = 0; i < 8; ++i) {
            int ss = (t >> 5) + i * 8;
            float v = cbb + bf2f(uu.st.rawbc[ss][jbc]) * cwb.x
                          + bf2f(uu.st.rawbc[ss + 1][jbc]) * cwb.y
                          + bf2f(uu.st.rawbc[ss + 2][jbc]) * cwb.z
                          + bf2f(uu.st.rawbc[ss + 3][jbc]) * cwb.w;
            v = fsilu(v);
            if (jbc < 16) Bb[ss][jbc] = f2bf(v);
            else {
                Cb[ss][jbc - 16] = f2bf(v);
                Cpost[((size_t)b * LL + l0 + ss) * DSTATE + (jbc - 16)] = v;
            }
        }
    }
    __syncthreads();

    const int w = t >> 6, l = t & 63;
    const int fr = l & 15, fq = l >> 4;

    // ---- phase 3: G = C.B^T (K=32 padded), mask -> Mb; fill BwT ----
    f32x4 gacc[4];
    {
        bf16x8 ca = *(const bf16x8*)&Cb[w * 16 + fr][fq * 8];
        #pragma unroll
        for (int jt = 0; jt < 4; ++jt) {
            bf16x8 bb = *(const bf16x8*)&Bb[jt * 16 + fr][fq * 8];
            f32x4 z = {0.f, 0.f, 0.f, 0.f};
            gacc[jt] = __builtin_amdgcn_mfma_f32_16x16x32_bf16(ca, bb, z, 0, 0, 0);
        }
    }
    #pragma unroll
    for (int jt = 0; jt < 4; ++jt) {
        int j = jt * 16 + fr;
        float laj = laa[j], dtj = dtt[j];
        #pragma unroll
        for (int r = 0; r < 4; ++r) {
            int i = w * 16 + fq * 4 + r;
            float m = (j <= i) ? gacc[jt][r] * fexp(laa[i] - laj) * dtj : 0.f;
            uu.ssd.Mb[i][j] = f2bf(m);
        }
    }
    #pragma unroll
    for (int i2 = 0; i2 < 4; ++i2) {
        int idx = t + i2 * 256;
        int n = idx & 15, jj = idx >> 4;
        uu.ssd.BwT[n][jj] = f2bf(ww[jj] * bf2f(Bb[jj][n]));
    }
    __syncthreads();

    // ---- phase 4: Y = M.X (+D skip) written back into Mb rows; S = X^T.(wB) ----
    {
        bf16x8 ma0 = *(const bf16x8*)&uu.ssd.Mb[w * 16 + fr][fq * 8];
        bf16x8 ma1 = *(const bf16x8*)&uu.ssd.Mb[w * 16 + fr][32 + fq * 8];
        #pragma unroll
        for (int pt = 0; pt < 4; ++pt) {
            bf16x8 xb0 = *(const bf16x8*)&XbT[pt * 16 + fr][fq * 8];
            bf16x8 xb1 = *(const bf16x8*)&XbT[pt * 16 + fr][32 + fq * 8];
            f32x4 acc = {0.f, 0.f, 0.f, 0.f};
            acc = __builtin_amdgcn_mfma_f32_16x16x32_bf16(ma0, xb0, acc, 0, 0, 0);
            acc = __builtin_amdgcn_mfma_f32_16x16x32_bf16(ma1, xb1, acc, 0, 0, 0);
            #pragma unroll
            for (int r = 0; r < 4; ++r) {
                int i = w * 16 + fq * 4 + r;          // this wave's own rows
                int p = pt * 16 + fr;
                float xv = bf2f(XbT[p][i]);
                uu.ssd.Mb[i][p] = f2bf(acc[r] + Dh * xv);
            }
        }
    }
    if (c < 15) {
        bf16x8 xa0 = *(const bf16x8*)&XbT[w * 16 + fr][fq * 8];
        bf16x8 xa1 = *(const bf16x8*)&XbT[w * 16 + fr][32 + fq * 8];
        bf16x8 bw0 = *(const bf16x8*)&uu.ssd.BwT[fr][fq * 8];
        bf16x8 bw1 = *(const bf16x8*)&uu.ssd.BwT[fr][32 + fq * 8];
        f32x4 acc = {0.f, 0.f, 0.f, 0.f};
        acc = __builtin_amdgcn_mfma_f32_16x16x32_bf16(xa0, bw0, acc, 0, 0, 0);
        acc = __builtin_amdgcn_mfma_f32_16x16x32_bf16(xa1, bw1, acc, 0, 0, 0);
        float* Sdst = h0buf + (((size_t)(b * 4 + h)) * NCH + (c + 1)) * 1024;
        #pragma unroll
        for (int r = 0; r < 4; ++r) {
            int p = w * 16 + fq * 4 + r;
            Sdst[p * 16 + fr] = acc[r];
        }
    }
    __syncthreads();

    // coalesced y store: 64 rows x 128B segments
    {
        ushort* ybase = y + ((size_t)b * LL + l0) * DINN + h * 64;
        #pragma unroll
        for (int ii = 0; ii < 2; ++ii) {
            int idx = t + ii * 256;
            int row = idx >> 3, c8 = (idx & 7) * 8;
            *(uint4*)&ybase[(size_t)row * DINN + c8] = *(const uint4*)&uu.ssd.Mb[row][c8];
        }
    }
}

// ---------------- K3b: chunk-level scan (16 chunks) ----------------
__global__ __launch_bounds__(256) void k3b_chunkscan(
        float* __restrict__ h0buf, const float* __restrict__ cdecbuf) {
    const int bh = blockIdx.x;
    const int t = threadIdx.x;
    float* base = h0buf + (size_t)bh * NCH * 1024;
    const float* cd = cdecbuf + (size_t)bh * LL;
    float4 run = {0.f, 0.f, 0.f, 0.f};
    *(float4*)&base[(size_t)t * 4] = run;
    #pragma unroll
    for (int c = 1; c < NCH; ++c) {
        float P = cd[c * CS - 1];
        float4 S = *(float4*)&base[(size_t)c * 1024 + t * 4];
        run.x = fmaf(run.x, P, S.x);
        run.y = fmaf(run.y, P, S.y);
        run.z = fmaf(run.z, P, S.z);
        run.w = fmaf(run.w, P, S.w);
        *(float4*)&base[(size_t)c * 1024 + t * 4] = run;
    }
}

// ------- K4: correction (H from global) + gate (pre-silu'd z) + RMSNorm + out_proj -------
__global__ __launch_bounds__(256) void k4_out(
        const ushort* __restrict__ ybf, const ushort* __restrict__ zbuf,
        const float* __restrict__ ngw, const ushort* __restrict__ Wob,
        const float* __restrict__ x, const float* __restrict__ h0buf,
        const float* __restrict__ cdecbuf, const float* __restrict__ Cpost,
        float* __restrict__ out) {
    __shared__ float Cs[32][16];
    __shared__ float cds[32][4];
    __shared__ ushort gb[32][264];      // 16.9 KB
    const int t = threadIdx.x;
    const int m0 = blockIdx.x * 32;
    const int b  = m0 >> 10;
    const int l0 = m0 & 1023;
    const int ck = l0 >> 6;
    const ushort* yb = ybf + (size_t)m0 * DINN;
    const ushort* zb = zbuf + (size_t)m0 * DINN;

    if (t < 128) {
        int r = t >> 2, n0 = (t & 3) * 4;
        *(float4*)&Cs[r][n0] = *(const float4*)&Cpost[((size_t)b * LL + l0 + r) * DSTATE + n0];
    } else {
        int tt = t - 128;
        int r = tt >> 2, hh = tt & 3;
        cds[r][hh] = cdecbuf[((size_t)(b * 4 + hh)) * LL + l0 + r];
    }

    const int ch4 = (t & 63) * 4;
    const int hh  = ch4 >> 6;
    const int p0  = ch4 & 63;
    const float* hbase = h0buf + (((size_t)(b * 4 + hh)) * NCH + ck) * 1024 + p0 * 16;
    float4 H[4][4];
    #pragma unroll
    for (int k = 0; k < 4; ++k)
        #pragma unroll
        for (int n4 = 0; n4 < 4; ++n4)
            H[k][n4] = *(const float4*)&hbase[k * 16 + n4 * 4];
    __syncthreads();

    const float4 ng4 = *(const float4*)&ngw[ch4];

    #pragma unroll
    for (int i = 0; i < 8; ++i) {
        int row = i * 4 + (t >> 6);
        ushort4 yu = *(const ushort4*)&yb[(size_t)row * DINN + ch4];
        ushort4 zu = *(const ushort4*)&zb[(size_t)row * DINN + ch4];
        float4 yv = { bf2f(yu.x), bf2f(yu.y), bf2f(yu.z), bf2f(yu.w) };
        float4 zv = { bf2f(zu.x), bf2f(zu.y), bf2f(zu.z), bf2f(zu.w) };  // silu(z)
        float4 C0 = *(const float4*)&Cs[row][0];
        float4 C1 = *(const float4*)&Cs[row][4];
        float4 C2 = *(const float4*)&Cs[row][8];
        float4 C3 = *(const float4*)&Cs[row][12];
        float cdv = cds[row][hh];
        float corr[4];
        #pragma unroll
        for (int k = 0; k < 4; ++k) {
            float s = H[k][0].x * C0.x + H[k][0].y * C0.y + H[k][0].z * C0.z + H[k][0].w * C0.w;
            s += H[k][1].x * C1.x + H[k][1].y * C1.y + H[k][1].z * C1.z + H[k][1].w * C1.w;
            s += H[k][2].x * C2.x + H[k][2].y * C2.y + H[k][2].z * C2.z + H[k][2].w * C2.w;
            s += H[k][3].x * C3.x + H[k][3].y * C3.y + H[k][3].z * C3.z + H[k][3].w * C3.w;
            corr[k] = s * cdv;
        }
        float4 gv;
        gv.x = (yv.x + corr[0]) * zv.x;
        gv.y = (yv.y + corr[1]) * zv.y;
        gv.z = (yv.z + corr[2]) * zv.z;
        gv.w = (yv.w + corr[3]) * zv.w;
        float s = gv.x * gv.x + gv.y * gv.y + gv.z * gv.z + gv.w * gv.w;
        s += __shfl_xor(s, 1);  s += __shfl_xor(s, 2);  s += __shfl_xor(s, 4);
        s += __shfl_xor(s, 8);  s += __shfl_xor(s, 16); s += __shfl_xor(s, 32);
        float rs = rsqrtf(s * (1.f / 256.f) + EPSF);
        ushort4 o;
        o.x = f2bf(gv.x * rs * ng4.x);
        o.y = f2bf(gv.y * rs * ng4.y);
        o.z = f2bf(gv.z * rs * ng4.z);
        o.w = f2bf(gv.w * rs * ng4.w);
        *(ushort4*)&gb[row][ch4] = o;
    }
    __syncthreads();

    const int w = t >> 6, l = t & 63;
    const int j = l & 15, kb = (l >> 4) * 8;
    bf16x8 bf[8];
    #pragma unroll
    for (int ks = 0; ks < 8; ++ks)
        bf[ks] = *(const bf16x8*)&Wob[(size_t)(16 * w + j) * DINN + ks * 32 + kb];
    #pragma unroll
    for (int mt = 0; mt < 2; ++mt) {
        f32x4 acc = {0.f, 0.f, 0.f, 0.f};
        #pragma unroll
        for (int ks = 0; ks < 8; ++ks) {
            bf16x8 af = *(const bf16x8*)&gb[mt * 16 + j][ks * 32 + kb];
            acc = __builtin_amdgcn_mfma_f32_16x16x32_bf16(af, bf[ks], acc, 0, 0, 0);
        }
        #pragma unroll
        for (int r = 0; r < 4; ++r) {
            size_t row = (size_t)m0 + mt * 16 + (l >> 4) * 4 + r;
            size_t oidx = row * 64 + 16 * w + j;
            out[oidx] = acc[r] + 2.f * x[oidx];
        }
    }
}

extern "C" void kernel_launch(void* const* d_in, const int* in_sizes, int n_in,
                              void* d_out, int out_size, void* d_ws, size_t ws_size,
                              hipStream_t stream) {
    const float* x          = (const float*)d_in[0];
    const float* in_proj_w  = (const float*)d_in[1];
    const float* conv_w     = (const float*)d_in[2];
    const float* conv_b     = (const float*)d_in[3];
    const float* dt_bias    = (const float*)d_in[4];
    const float* A_log      = (const float*)d_in[5];
    const float* D          = (const float*)d_in[6];
    const float* norm_gate  = (const float*)d_in[7];
    const float* out_proj_w = (const float*)d_in[8];
    const float* block_norm = (const float*)d_in[9];
    float* out = (float*)d_out;

    float* h0b   = (float*)d_ws;                               //  2,097,152 f32
    float* cdec  = h0b  + (size_t)BB * NHEADS * NCH * 1024;    //    131,072 f32
    float* Cp    = cdec + (size_t)BB * NHEADS * LL;            //    524,288 f32
    float* dtb   = Cp   + (size_t)BB * LL * DSTATE;            //    131,072 f32
    ushort* ybf  = (ushort*)(dtb + (size_t)BB * NHEADS * LL);  //  8,388,608 us
    ushort* zbuf = ybf  + (size_t)BB * LL * DINN;              //  8,388,608 us
    ushort* xbc  = zbuf + (size_t)BB * LL * DINN;              //  9,437,184 us
    ushort* Wb   = xbc  + (size_t)BB * LL * 288;               //     35,072 us
    ushort* Wob  = Wb   + (size_t)DINPROJ * 64;                //     16,384 us

    kwcvt<<<201, 256, 0, stream>>>(in_proj_w, out_proj_w, Wb, Wob);
    k1_mfma<<<1024, 256, 0, stream>>>(x, Wb, block_norm, in_proj_w, dt_bias, zbuf, xbc, dtb);
    k3a_ssd<<<2048, 256, 0, stream>>>(xbc, dtb, conv_w, conv_b, A_log, D, ybf, h0b, cdec, Cp);
    k3b_chunkscan<<<128, 256, 0, stream>>>(h0b, cdec);
    k4_out<<<1024, 256, 0, stream>>>(ybf, zbuf, norm_gate, Wob, x, h0b, cdec, Cp, out);
}

// Round 11
// 72.430 us; speedup vs baseline: 1.5535x; 1.0760x over previous
//
#include <hip/hip_runtime.h>
#include <math.h>

#define BB 32
#define LL 1024
#define DIMM 64
#define DINN 256
#define NHEADS 4
#define DSTATE 16
#define DINPROJ 548
#define EPSF 1e-5f
#define NCH 16    // chunks per sequence
#define CS 64     // chunk size

typedef __attribute__((ext_vector_type(8))) short bf16x8;
typedef __attribute__((ext_vector_type(4))) float f32x4;

__device__ inline ushort f2bf(float f) {
    union { float f; unsigned u; } v; v.f = f;
    unsigned r = (v.u + 0x7FFFu + ((v.u >> 16) & 1u)) >> 16;
    return (ushort)r;
}
__device__ inline float bf2f(ushort u) {
    union { float f; unsigned u; } v; v.u = ((unsigned)u) << 16; return v.f;
}
__device__ inline float fexp(float v) { return __expf(v); }
__device__ inline float fsilu(float v) {
    return v * __builtin_amdgcn_rcpf(1.f + __expf(-v));
}

// ---------------- K0: convert weights to bf16 ----------------
__global__ __launch_bounds__(256) void kwcvt(
        const float* __restrict__ Win, const float* __restrict__ Wout,
        ushort* __restrict__ Wb, ushort* __restrict__ Wob) {
    int i = blockIdx.x * 256 + threadIdx.x;
    if (i < DINPROJ * 64) Wb[i] = f2bf(Win[i]);
    else if (i < DINPROJ * 64 + 64 * DINN) {
        int j = i - DINPROJ * 64;
        Wob[j] = f2bf(Wout[j]);
    }
}

// -- K1: RMSNorm + in_proj (bf16 MFMA) + fp32 dt + silu(z) + coalesced stores --
__global__ __launch_bounds__(256) void k1_mfma(
        const float* __restrict__ x, const ushort* __restrict__ Wb,
        const float* __restrict__ bnw, const float* __restrict__ Wfp,
        const float* __restrict__ dt_bias,
        ushort* __restrict__ zbuf, ushort* __restrict__ xbcbuf,
        float* __restrict__ dtbuf) {
    __shared__ __align__(16) union {
        struct { float u[32][68]; float wdt[4][68]; } a;   // 9.8 KB
        ushort ob[32][552];                                 // 35.3 KB
    } s;
    __shared__ float rstd[32];
    const int t = threadIdx.x;
    const int m0 = blockIdx.x * 32;
    const int b = m0 >> 10;
    const int lbase = m0 & 1023;

    const float* xrow = x + (size_t)m0 * 64;
    #pragma unroll
    for (int i = 0; i < 2; ++i) {
        int idx = t + i * 256;
        float4 v = ((const float4*)xrow)[idx];
        *(float4*)&s.a.u[idx >> 4][(idx & 15) * 4] = v;
    }
    s.a.wdt[t >> 6][t & 63] = Wfp[(size_t)(544 + (t >> 6)) * 64 + (t & 63)] * bnw[t & 63];
    __syncthreads();
    {
        int row = t >> 3, part = t & 7;
        float ss = 0.f;
        #pragma unroll
        for (int j = 0; j < 8; ++j) { float v = s.a.u[row][part * 8 + j]; ss = fmaf(v, v, ss); }
        ss += __shfl_xor(ss, 1); ss += __shfl_xor(ss, 2); ss += __shfl_xor(ss, 4);
        if (part == 0) rstd[row] = rsqrtf(ss * (1.f / 64.f) + EPSF);
    }
    __syncthreads();

    const int w = t >> 6, l = t & 63;
    const int a = l & 15, kb = (l >> 4) * 8;

    float4 bw[2][2];
    bw[0][0] = *(const float4*)&bnw[kb];
    bw[0][1] = *(const float4*)&bnw[kb + 4];
    bw[1][0] = *(const float4*)&bnw[32 + kb];
    bw[1][1] = *(const float4*)&bnw[32 + kb + 4];

    bf16x8 af[2][2];
    #pragma unroll
    for (int mt = 0; mt < 2; ++mt) {
        float rs = rstd[mt * 16 + a];
        #pragma unroll
        for (int kk = 0; kk < 2; ++kk) {
            float4 v0 = *(const float4*)&s.a.u[mt * 16 + a][kk * 32 + kb];
            float4 v1 = *(const float4*)&s.a.u[mt * 16 + a][kk * 32 + kb + 4];
            ushort* p = (ushort*)&af[mt][kk];
            p[0] = f2bf(v0.x * rs * bw[kk][0].x);
            p[1] = f2bf(v0.y * rs * bw[kk][0].y);
            p[2] = f2bf(v0.z * rs * bw[kk][0].z);
            p[3] = f2bf(v0.w * rs * bw[kk][0].w);
            p[4] = f2bf(v1.x * rs * bw[kk][1].x);
            p[5] = f2bf(v1.y * rs * bw[kk][1].y);
            p[6] = f2bf(v1.z * rs * bw[kk][1].z);
            p[7] = f2bf(v1.w * rs * bw[kk][1].w);
        }
    }

    if (t < 128) {
        int row = t >> 2, h = t & 3;
        const float* ur = s.a.u[row];
        const float* wr = s.a.wdt[h];
        float sd = 0.f;
        #pragma unroll
        for (int k4 = 0; k4 < 16; ++k4) {
            float4 uv = *(const float4*)&ur[k4 * 4];
            float4 wv = *(const float4*)&wr[k4 * 4];
            sd = fmaf(uv.x, wv.x, sd); sd = fmaf(uv.y, wv.y, sd);
            sd = fmaf(uv.z, wv.z, sd); sd = fmaf(uv.w, wv.w, sd);
        }
        sd = sd * rstd[row] + dt_bias[h];
        sd = fmaxf(sd, 0.f) + log1pf(expf(-fabsf(sd)));   // keep precise
        dtbuf[((size_t)(b * 4 + h)) * LL + lbase + row] = sd;
    }
    __syncthreads();   // u/wdt dead; ob may now be written

    for (int nt = w; nt < 34; nt += 4) {
        const ushort* wbp = Wb + (size_t)(nt * 16 + a) * 64 + kb;
        bf16x8 b0 = *(const bf16x8*)wbp;
        bf16x8 b1 = *(const bf16x8*)(wbp + 32);
        #pragma unroll
        for (int mt = 0; mt < 2; ++mt) {
            f32x4 acc = {0.f, 0.f, 0.f, 0.f};
            acc = __builtin_amdgcn_mfma_f32_16x16x32_bf16(af[mt][0], b0, acc, 0, 0, 0);
            acc = __builtin_amdgcn_mfma_f32_16x16x32_bf16(af[mt][1], b1, acc, 0, 0, 0);
            int row0 = mt * 16 + (l >> 4) * 4;
            int col = nt * 16 + a;
            if (nt < 16) {
                #pragma unroll
                for (int r = 0; r < 4; ++r) s.ob[row0 + r][col] = f2bf(fsilu(acc[r]));
            } else {
                #pragma unroll
                for (int r = 0; r < 4; ++r) s.ob[row0 + r][col] = f2bf(acc[r]);
            }
        }
    }
    __syncthreads();

    for (int i = t; i < 1024; i += 256) {
        int row = i >> 5, c8 = (i & 31) * 8;
        *(uint4*)&zbuf[(size_t)(m0 + row) * DINN + c8] = *(const uint4*)&s.ob[row][c8];
    }
    for (int i = t; i < 1152; i += 256) {
        int row = i / 36, c8 = (i % 36) * 8;
        *(uint4*)&xbcbuf[(size_t)(m0 + row) * 288 + c8] = *(const uint4*)&s.ob[row][256 + c8];
    }
}

// ---------------- K3a: SSD chunked scan via MFMA (bf16 in/out) ----------------
__global__ __launch_bounds__(256) void k3a_ssd(
        const ushort* __restrict__ xbcbuf, const float* __restrict__ dtbuf,
        const float* __restrict__ conv_w, const float* __restrict__ conv_b,
        const float* __restrict__ A_log, const float* __restrict__ Dp,
        ushort* __restrict__ y, float* __restrict__ h0buf,
        float* __restrict__ cdecbuf, ushort* __restrict__ Cpost) {
    const int bid = blockIdx.x;
    const int c = bid & 15, h = (bid >> 4) & 3, b = bid >> 6;
    const int t = threadIdx.x;

    __shared__ __align__(16) union {
        struct { ushort rawx[67][64]; ushort rawbc[67][32]; } st;  // 12.9 KB
        struct { ushort Mb[64][72]; ushort BwT[16][72]; } ssd;     // 11.5 KB
    } uu;
    __shared__ ushort XbT[64][72];
    __shared__ ushort Bb[64][40];
    __shared__ ushort Cb[64][40];
    __shared__ float dtt[64], laa[64], ww[64];

    const float A  = -expf(A_log[h]);
    const float Dh = Dp[h];
    const int l0 = c * CS;
    const ushort* xb = xbcbuf + (size_t)b * LL * 288;

    for (int i = t; i < 67 * 32; i += 256) {
        int r = i >> 5, cu = i & 31;
        int l = l0 - 3 + r;
        ((uint*)&uu.st.rawx[r][0])[cu] =
            (l >= 0) ? ((const uint*)(xb + (size_t)l * 288 + h * 64))[cu] : 0u;
    }
    for (int i = t; i < 67 * 16; i += 256) {
        int r = i >> 4, cu = i & 15;
        int l = l0 - 3 + r;
        ((uint*)&uu.st.rawbc[r][0])[cu] =
            (l >= 0) ? ((const uint*)(xb + (size_t)l * 288 + 256))[cu] : 0u;
    }
    {
        uint* pz = (uint*)&Bb[0][0];
        for (int i = t; i < 64 * 40 / 2; i += 256) pz[i] = 0;
        uint* pz2 = (uint*)&Cb[0][0];
        for (int i = t; i < 64 * 40 / 2; i += 256) pz2[i] = 0;
    }
    if (t < 64) {
        float dv = dtbuf[((size_t)(b * 4 + h)) * LL + l0 + t];
        float run = dv * A;
        #pragma unroll
        for (int off = 1; off < 64; off <<= 1) {
            float o = __shfl_up(run, off, 64);
            if (t >= off) run += o;
        }
        dtt[t] = dv;
        laa[t] = run;
        cdecbuf[((size_t)(b * 4 + h)) * LL + l0 + t] = fexp(run);
        float laEnd = __shfl(run, 63, 64);
        ww[t] = dv * fexp(laEnd - run);
    }
    __syncthreads();

    {
        const int jx = t & 63;
        const int cx = h * 64 + jx;
        const float4 cwx = *(const float4*)&conv_w[cx * 4];
        const float  cbx = conv_b[cx];
        #pragma unroll
        for (int i = 0; i < 16; ++i) {
            int ss = (t >> 6) + i * 4;
            float v = cbx + bf2f(uu.st.rawx[ss][jx]) * cwx.x
                          + bf2f(uu.st.rawx[ss + 1][jx]) * cwx.y
                          + bf2f(uu.st.rawx[ss + 2][jx]) * cwx.z
                          + bf2f(uu.st.rawx[ss + 3][jx]) * cwx.w;
            XbT[jx][ss] = f2bf(fsilu(v));
        }
        const int jbc = t & 31, cbc = 256 + jbc;
        const float4 cwb = *(const float4*)&conv_w[cbc * 4];
        const float  cbb = conv_b[cbc];
        #pragma unroll
        for (int i = 0; i < 8; ++i) {
            int ss = (t >> 5) + i * 8;
            float v = cbb + bf2f(uu.st.rawbc[ss][jbc]) * cwb.x
                          + bf2f(uu.st.rawbc[ss + 1][jbc]) * cwb.y
                          + bf2f(uu.st.rawbc[ss + 2][jbc]) * cwb.z
                          + bf2f(uu.st.rawbc[ss + 3][jbc]) * cwb.w;
            v = fsilu(v);
            if (jbc < 16) Bb[ss][jbc] = f2bf(v);
            else {
                ushort bv = f2bf(v);
                Cb[ss][jbc - 16] = bv;
                Cpost[((size_t)b * LL + l0 + ss) * DSTATE + (jbc - 16)] = bv;
            }
        }
    }
    __syncthreads();

    const int w = t >> 6, l = t & 63;
    const int fr = l & 15, fq = l >> 4;

    f32x4 gacc[4];
    {
        bf16x8 ca = *(const bf16x8*)&Cb[w * 16 + fr][fq * 8];
        #pragma unroll
        for (int jt = 0; jt < 4; ++jt) {
            bf16x8 bb = *(const bf16x8*)&Bb[jt * 16 + fr][fq * 8];
            f32x4 z = {0.f, 0.f, 0.f, 0.f};
            gacc[jt] = __builtin_amdgcn_mfma_f32_16x16x32_bf16(ca, bb, z, 0, 0, 0);
        }
    }
    #pragma unroll
    for (int jt = 0; jt < 4; ++jt) {
        int j = jt * 16 + fr;
        float laj = laa[j], dtj = dtt[j];
        #pragma unroll
        for (int r = 0; r < 4; ++r) {
            int i = w * 16 + fq * 4 + r;
            float m = (j <= i) ? gacc[jt][r] * fexp(laa[i] - laj) * dtj : 0.f;
            uu.ssd.Mb[i][j] = f2bf(m);
        }
    }
    #pragma unroll
    for (int i2 = 0; i2 < 4; ++i2) {
        int idx = t + i2 * 256;
        int n = idx & 15, jj = idx >> 4;
        uu.ssd.BwT[n][jj] = f2bf(ww[jj] * bf2f(Bb[jj][n]));
    }
    __syncthreads();

    {
        bf16x8 ma0 = *(const bf16x8*)&uu.ssd.Mb[w * 16 + fr][fq * 8];
        bf16x8 ma1 = *(const bf16x8*)&uu.ssd.Mb[w * 16 + fr][32 + fq * 8];
        #pragma unroll
        for (int pt = 0; pt < 4; ++pt) {
            bf16x8 xb0 = *(const bf16x8*)&XbT[pt * 16 + fr][fq * 8];
            bf16x8 xb1 = *(const bf16x8*)&XbT[pt * 16 + fr][32 + fq * 8];
            f32x4 acc = {0.f, 0.f, 0.f, 0.f};
            acc = __builtin_amdgcn_mfma_f32_16x16x32_bf16(ma0, xb0, acc, 0, 0, 0);
            acc = __builtin_amdgcn_mfma_f32_16x16x32_bf16(ma1, xb1, acc, 0, 0, 0);
            #pragma unroll
            for (int r = 0; r < 4; ++r) {
                int i = w * 16 + fq * 4 + r;
                int p = pt * 16 + fr;
                float xv = bf2f(XbT[p][i]);
                uu.ssd.Mb[i][p] = f2bf(acc[r] + Dh * xv);
            }
        }
    }
    if (c < 15) {
        bf16x8 xa0 = *(const bf16x8*)&XbT[w * 16 + fr][fq * 8];
        bf16x8 xa1 = *(const bf16x8*)&XbT[w * 16 + fr][32 + fq * 8];
        bf16x8 bw0 = *(const bf16x8*)&uu.ssd.BwT[fr][fq * 8];
        bf16x8 bw1 = *(const bf16x8*)&uu.ssd.BwT[fr][32 + fq * 8];
        f32x4 acc = {0.f, 0.f, 0.f, 0.f};
        acc = __builtin_amdgcn_mfma_f32_16x16x32_bf16(xa0, bw0, acc, 0, 0, 0);
        acc = __builtin_amdgcn_mfma_f32_16x16x32_bf16(xa1, bw1, acc, 0, 0, 0);
        float* Sdst = h0buf + (((size_t)(b * 4 + h)) * NCH + (c + 1)) * 1024;
        #pragma unroll
        for (int r = 0; r < 4; ++r) {
            int p = w * 16 + fq * 4 + r;
            Sdst[p * 16 + fr] = acc[r];
        }
    }
    __syncthreads();

    {
        ushort* ybase = y + ((size_t)b * LL + l0) * DINN + h * 64;
        #pragma unroll
        for (int ii = 0; ii < 2; ++ii) {
            int idx = t + ii * 256;
            int row = idx >> 3, c8 = (idx & 7) * 8;
            *(uint4*)&ybase[(size_t)row * DINN + c8] = *(const uint4*)&uu.ssd.Mb[row][c8];
        }
    }
}

// ---------------- K3b: chunk-level scan (16 chunks) ----------------
__global__ __launch_bounds__(256) void k3b_chunkscan(
        float* __restrict__ h0buf, const float* __restrict__ cdecbuf) {
    const int bh = blockIdx.x;
    const int t = threadIdx.x;
    float* base = h0buf + (size_t)bh * NCH * 1024;
    const float* cd = cdecbuf + (size_t)bh * LL;
    float4 run = {0.f, 0.f, 0.f, 0.f};
    *(float4*)&base[(size_t)t * 4] = run;
    #pragma unroll
    for (int c = 1; c < NCH; ++c) {
        float P = cd[c * CS - 1];
        float4 S = *(float4*)&base[(size_t)c * 1024 + t * 4];
        run.x = fmaf(run.x, P, S.x);
        run.y = fmaf(run.y, P, S.y);
        run.z = fmaf(run.z, P, S.z);
        run.w = fmaf(run.w, P, S.w);
        *(float4*)&base[(size_t)c * 1024 + t * 4] = run;
    }
}

// ------- K4: M=64 tile; correction (H regs) + gate + RMSNorm + out_proj -------
// grid 512 = (b, chunk); block 256 = 4 waves
__global__ __launch_bounds__(256) void k4_out(
        const ushort* __restrict__ ybf, const ushort* __restrict__ zbuf,
        const float* __restrict__ ngw, const ushort* __restrict__ Wob,
        const float* __restrict__ x, const float* __restrict__ h0buf,
        const float* __restrict__ cdecbuf, const ushort* __restrict__ Cpost,
        float* __restrict__ out) {
    __shared__ float Cs[64][16];        // 4 KB
    __shared__ float cds[64][4];        // 1 KB
    __shared__ ushort gb[64][264];      // 33.8 KB
    const int t = threadIdx.x;
    const int m0 = blockIdx.x * 64;
    const int b  = m0 >> 10;
    const int l0 = m0 & 1023;
    const int ck = l0 >> 6;             // exactly one chunk per block
    const ushort* yb = ybf + (size_t)m0 * DINN;
    const ushort* zb = zbuf + (size_t)m0 * DINN;

    // stage C (bf16 -> f32) and cdec: every thread does one of each
    {
        int r = t >> 2, n0 = (t & 3) * 4;
        ushort4 cu4 = *(const ushort4*)&Cpost[((size_t)b * LL + l0 + r) * DSTATE + n0];
        Cs[r][n0 + 0] = bf2f(cu4.x);
        Cs[r][n0 + 1] = bf2f(cu4.y);
        Cs[r][n0 + 2] = bf2f(cu4.z);
        Cs[r][n0 + 3] = bf2f(cu4.w);
        int hh2 = t & 3;
        cds[r][hh2] = cdecbuf[((size_t)(b * 4 + hh2)) * LL + l0 + r];
    }

    // H registers straight from global (L2-resident slab)
    const int ch4 = (t & 63) * 4;
    const int hh  = ch4 >> 6;
    const int p0  = ch4 & 63;
    const float* hbase = h0buf + (((size_t)(b * 4 + hh)) * NCH + ck) * 1024 + p0 * 16;
    float4 H[4][4];
    #pragma unroll
    for (int k = 0; k < 4; ++k)
        #pragma unroll
        for (int n4 = 0; n4 < 4; ++n4)
            H[k][n4] = *(const float4*)&hbase[k * 16 + n4 * 4];
    __syncthreads();

    const float4 ng4 = *(const float4*)&ngw[ch4];

    #pragma unroll
    for (int i = 0; i < 16; ++i) {
        int row = i * 4 + (t >> 6);     // row entirely within this wave
        ushort4 yu = *(const ushort4*)&yb[(size_t)row * DINN + ch4];
        ushort4 zu = *(const ushort4*)&zb[(size_t)row * DINN + ch4];
        float4 yv = { bf2f(yu.x), bf2f(yu.y), bf2f(yu.z), bf2f(yu.w) };
        float4 zv = { bf2f(zu.x), bf2f(zu.y), bf2f(zu.z), bf2f(zu.w) };  // silu(z)
        float4 C0 = *(const float4*)&Cs[row][0];
        float4 C1 = *(const float4*)&Cs[row][4];
        float4 C2 = *(const float4*)&Cs[row][8];
        float4 C3 = *(const float4*)&Cs[row][12];
        float cdv = cds[row][hh];
        float corr[4];
        #pragma unroll
        for (int k = 0; k < 4; ++k) {
            float s = H[k][0].x * C0.x + H[k][0].y * C0.y + H[k][0].z * C0.z + H[k][0].w * C0.w;
            s += H[k][1].x * C1.x + H[k][1].y * C1.y + H[k][1].z * C1.z + H[k][1].w * C1.w;
            s += H[k][2].x * C2.x + H[k][2].y * C2.y + H[k][2].z * C2.z + H[k][2].w * C2.w;
            s += H[k][3].x * C3.x + H[k][3].y * C3.y + H[k][3].z * C3.z + H[k][3].w * C3.w;
            corr[k] = s * cdv;
        }
        float4 gv;
        gv.x = (yv.x + corr[0]) * zv.x;
        gv.y = (yv.y + corr[1]) * zv.y;
        gv.z = (yv.z + corr[2]) * zv.z;
        gv.w = (yv.w + corr[3]) * zv.w;
        float s = gv.x * gv.x + gv.y * gv.y + gv.z * gv.z + gv.w * gv.w;
        s += __shfl_xor(s, 1);  s += __shfl_xor(s, 2);  s += __shfl_xor(s, 4);
        s += __shfl_xor(s, 8);  s += __shfl_xor(s, 16); s += __shfl_xor(s, 32);
        float rs = rsqrtf(s * (1.f / 256.f) + EPSF);
        ushort4 o;
        o.x = f2bf(gv.x * rs * ng4.x);
        o.y = f2bf(gv.y * rs * ng4.y);
        o.z = f2bf(gv.z * rs * ng4.z);
        o.w = f2bf(gv.w * rs * ng4.w);
        *(ushort4*)&gb[row][ch4] = o;
    }
    __syncthreads();

    const int w = t >> 6, l = t & 63;
    const int j = l & 15, kb = (l >> 4) * 8;
    bf16x8 bf[8];
    #pragma unroll
    for (int ks = 0; ks < 8; ++ks)
        bf[ks] = *(const bf16x8*)&Wob[(size_t)(16 * w + j) * DINN + ks * 32 + kb];
    #pragma unroll
    for (int mt = 0; mt < 4; ++mt) {
        f32x4 acc = {0.f, 0.f, 0.f, 0.f};
        #pragma unroll
        for (int ks = 0; ks < 8; ++ks) {
            bf16x8 af = *(const bf16x8*)&gb[mt * 16 + j][ks * 32 + kb];
            acc = __builtin_amdgcn_mfma_f32_16x16x32_bf16(af, bf[ks], acc, 0, 0, 0);
        }
        #pragma unroll
        for (int r = 0; r < 4; ++r) {
            size_t row = (size_t)m0 + mt * 16 + (l >> 4) * 4 + r;
            size_t oidx = row * 64 + 16 * w + j;
            out[oidx] = acc[r] + 2.f * x[oidx];
        }
    }
}

extern "C" void kernel_launch(void* const* d_in, const int* in_sizes, int n_in,
                              void* d_out, int out_size, void* d_ws, size_t ws_size,
                              hipStream_t stream) {
    const float* x          = (const float*)d_in[0];
    const float* in_proj_w  = (const float*)d_in[1];
    const float* conv_w     = (const float*)d_in[2];
    const float* conv_b     = (const float*)d_in[3];
    const float* dt_bias    = (const float*)d_in[4];
    const float* A_log      = (const float*)d_in[5];
    const float* D          = (const float*)d_in[6];
    const float* norm_gate  = (const float*)d_in[7];
    const float* out_proj_w = (const float*)d_in[8];
    const float* block_norm = (const float*)d_in[9];
    float* out = (float*)d_out;

    float* h0b   = (float*)d_ws;                               //  2,097,152 f32
    float* cdec  = h0b  + (size_t)BB * NHEADS * NCH * 1024;    //    131,072 f32
    float* dtb   = cdec + (size_t)BB * NHEADS * LL;            //    131,072 f32
    ushort* Cp   = (ushort*)(dtb + (size_t)BB * NHEADS * LL);  //    524,288 us
    ushort* ybf  = Cp   + (size_t)BB * LL * DSTATE;            //  8,388,608 us
    ushort* zbuf = ybf  + (size_t)BB * LL * DINN;              //  8,388,608 us
    ushort* xbc  = zbuf + (size_t)BB * LL * DINN;              //  9,437,184 us
    ushort* Wb   = xbc  + (size_t)BB * LL * 288;               //     35,072 us
    ushort* Wob  = Wb   + (size_t)DINPROJ * 64;                //     16,384 us

    kwcvt<<<201, 256, 0, stream>>>(in_proj_w, out_proj_w, Wb, Wob);
    k1_mfma<<<1024, 256, 0, stream>>>(x, Wb, block_norm, in_proj_w, dt_bias, zbuf, xbc, dtb);
    k3a_ssd<<<2048, 256, 0, stream>>>(xbc, dtb, conv_w, conv_b, A_log, D, ybf, h0b, cdec, Cp);
    k3b_chunkscan<<<128, 256, 0, stream>>>(h0b, cdec);
    k4_out<<<512, 256, 0, stream>>>(ybf, zbuf, norm_gate, Wob, x, h0b, cdec, Cp, out);
}

// Round 12
// 70.322 us; speedup vs baseline: 1.6001x; 1.0300x over previous
//
#include <hip/hip_runtime.h>
#include <math.h>

#define BB 32
#define LL 1024
#define DIMM 64
#define DINN 256
#define NHEADS 4
#define DSTATE 16
#define DINPROJ 548
#define EPSF 1e-5f
#define NCH 16    // chunks per sequence
#define CS 64     // chunk size

typedef __attribute__((ext_vector_type(8))) short bf16x8;
typedef __attribute__((ext_vector_type(4))) float f32x4;

__device__ inline ushort f2bf(float f) {
    union { float f; unsigned u; } v; v.f = f;
    unsigned r = (v.u + 0x7FFFu + ((v.u >> 16) & 1u)) >> 16;
    return (ushort)r;
}
__device__ inline float bf2f(ushort u) {
    union { float f; unsigned u; } v; v.u = ((unsigned)u) << 16; return v.f;
}
__device__ inline float fexp(float v) { return __expf(v); }
__device__ inline float fsilu(float v) {
    return v * __builtin_amdgcn_rcpf(1.f + __expf(-v));
}

// ---------------- K0: convert weights to bf16 ----------------
__global__ __launch_bounds__(256) void kwcvt(
        const float* __restrict__ Win, const float* __restrict__ Wout,
        ushort* __restrict__ Wb, ushort* __restrict__ Wob) {
    int i = blockIdx.x * 256 + threadIdx.x;
    if (i < DINPROJ * 64) Wb[i] = f2bf(Win[i]);
    else if (i < DINPROJ * 64 + 64 * DINN) {
        int j = i - DINPROJ * 64;
        Wob[j] = f2bf(Wout[j]);
    }
}

// -- K1: RMSNorm + in_proj (bf16 MFMA) + fp32 dt + silu(z) + coalesced stores --
__global__ __launch_bounds__(256) void k1_mfma(
        const float* __restrict__ x, const ushort* __restrict__ Wb,
        const float* __restrict__ bnw, const float* __restrict__ Wfp,
        const float* __restrict__ dt_bias,
        ushort* __restrict__ zbuf, ushort* __restrict__ xbcbuf,
        float* __restrict__ dtbuf) {
    __shared__ __align__(16) union {
        struct { float u[32][68]; float wdt[4][68]; } a;   // 9.8 KB
        ushort ob[32][552];                                 // 35.3 KB
    } s;
    __shared__ float rstd[32];
    const int t = threadIdx.x;
    const int m0 = blockIdx.x * 32;
    const int b = m0 >> 10;
    const int lbase = m0 & 1023;

    const float* xrow = x + (size_t)m0 * 64;
    #pragma unroll
    for (int i = 0; i < 2; ++i) {
        int idx = t + i * 256;
        float4 v = ((const float4*)xrow)[idx];
        *(float4*)&s.a.u[idx >> 4][(idx & 15) * 4] = v;
    }
    s.a.wdt[t >> 6][t & 63] = Wfp[(size_t)(544 + (t >> 6)) * 64 + (t & 63)] * bnw[t & 63];
    __syncthreads();
    {
        int row = t >> 3, part = t & 7;
        float ss = 0.f;
        #pragma unroll
        for (int j = 0; j < 8; ++j) { float v = s.a.u[row][part * 8 + j]; ss = fmaf(v, v, ss); }
        ss += __shfl_xor(ss, 1); ss += __shfl_xor(ss, 2); ss += __shfl_xor(ss, 4);
        if (part == 0) rstd[row] = rsqrtf(ss * (1.f / 64.f) + EPSF);
    }
    __syncthreads();

    const int w = t >> 6, l = t & 63;
    const int a = l & 15, kb = (l >> 4) * 8;

    float4 bw[2][2];
    bw[0][0] = *(const float4*)&bnw[kb];
    bw[0][1] = *(const float4*)&bnw[kb + 4];
    bw[1][0] = *(const float4*)&bnw[32 + kb];
    bw[1][1] = *(const float4*)&bnw[32 + kb + 4];

    bf16x8 af[2][2];
    #pragma unroll
    for (int mt = 0; mt < 2; ++mt) {
        float rs = rstd[mt * 16 + a];
        #pragma unroll
        for (int kk = 0; kk < 2; ++kk) {
            float4 v0 = *(const float4*)&s.a.u[mt * 16 + a][kk * 32 + kb];
            float4 v1 = *(const float4*)&s.a.u[mt * 16 + a][kk * 32 + kb + 4];
            ushort* p = (ushort*)&af[mt][kk];
            p[0] = f2bf(v0.x * rs * bw[kk][0].x);
            p[1] = f2bf(v0.y * rs * bw[kk][0].y);
            p[2] = f2bf(v0.z * rs * bw[kk][0].z);
            p[3] = f2bf(v0.w * rs * bw[kk][0].w);
            p[4] = f2bf(v1.x * rs * bw[kk][1].x);
            p[5] = f2bf(v1.y * rs * bw[kk][1].y);
            p[6] = f2bf(v1.z * rs * bw[kk][1].z);
            p[7] = f2bf(v1.w * rs * bw[kk][1].w);
        }
    }

    if (t < 128) {
        int row = t >> 2, h = t & 3;
        const float* ur = s.a.u[row];
        const float* wr = s.a.wdt[h];
        float sd = 0.f;
        #pragma unroll
        for (int k4 = 0; k4 < 16; ++k4) {
            float4 uv = *(const float4*)&ur[k4 * 4];
            float4 wv = *(const float4*)&wr[k4 * 4];
            sd = fmaf(uv.x, wv.x, sd); sd = fmaf(uv.y, wv.y, sd);
            sd = fmaf(uv.z, wv.z, sd); sd = fmaf(uv.w, wv.w, sd);
        }
        sd = sd * rstd[row] + dt_bias[h];
        sd = fmaxf(sd, 0.f) + log1pf(expf(-fabsf(sd)));   // keep precise
        dtbuf[((size_t)(b * 4 + h)) * LL + lbase + row] = sd;
    }
    __syncthreads();   // u/wdt dead; ob may now be written

    for (int nt = w; nt < 34; nt += 4) {
        const ushort* wbp = Wb + (size_t)(nt * 16 + a) * 64 + kb;
        bf16x8 b0 = *(const bf16x8*)wbp;
        bf16x8 b1 = *(const bf16x8*)(wbp + 32);
        #pragma unroll
        for (int mt = 0; mt < 2; ++mt) {
            f32x4 acc = {0.f, 0.f, 0.f, 0.f};
            acc = __builtin_amdgcn_mfma_f32_16x16x32_bf16(af[mt][0], b0, acc, 0, 0, 0);
            acc = __builtin_amdgcn_mfma_f32_16x16x32_bf16(af[mt][1], b1, acc, 0, 0, 0);
            int row0 = mt * 16 + (l >> 4) * 4;
            int col = nt * 16 + a;
            if (nt < 16) {
                #pragma unroll
                for (int r = 0; r < 4; ++r) s.ob[row0 + r][col] = f2bf(fsilu(acc[r]));
            } else {
                #pragma unroll
                for (int r = 0; r < 4; ++r) s.ob[row0 + r][col] = f2bf(acc[r]);
            }
        }
    }
    __syncthreads();

    for (int i = t; i < 1024; i += 256) {
        int row = i >> 5, c8 = (i & 31) * 8;
        *(uint4*)&zbuf[(size_t)(m0 + row) * DINN + c8] = *(const uint4*)&s.ob[row][c8];
    }
    for (int i = t; i < 1152; i += 256) {
        int row = i / 36, c8 = (i % 36) * 8;
        *(uint4*)&xbcbuf[(size_t)(m0 + row) * 288 + c8] = *(const uint4*)&s.ob[row][256 + c8];
    }
}

// ---------------- K3a: SSD chunked scan via MFMA (bf16 in/out) ----------------
// grid 2048 = (b,h,c); block 256 = 4 waves
__global__ __launch_bounds__(256) void k3a_ssd(
        const ushort* __restrict__ xbcbuf, const float* __restrict__ dtbuf,
        const float* __restrict__ conv_w, const float* __restrict__ conv_b,
        const float* __restrict__ A_log, const float* __restrict__ Dp,
        ushort* __restrict__ y, float* __restrict__ h0buf,
        float* __restrict__ cdecbuf, ushort* __restrict__ Cpost) {
    const int bid = blockIdx.x;
    const int c = bid & 15, h = (bid >> 4) & 3, b = bid >> 6;
    const int t = threadIdx.x;

    __shared__ __align__(16) union {
        struct { ushort rawx[67][64]; ushort rawbc[67][32]; } st;  // 12.9 KB
        struct { ushort Mb[64][72]; ushort BwT[16][72]; } ssd;     // 11.5 KB
    } uu;
    __shared__ ushort XbT[64][72];
    __shared__ ushort Bb[64][40];
    __shared__ ushort Cb[64][40];
    __shared__ float dtt[64], laa[64], ww[64];

    const float A  = -expf(A_log[h]);
    const float Dh = Dp[h];
    const int l0 = c * CS;
    const ushort* xb = xbcbuf + (size_t)b * LL * 288;

    // ---- phase 1: stage raw (bf16) + pad-zero (cols 16..31 only) + dt scan ----
    for (int i = t; i < 67 * 32; i += 256) {
        int r = i >> 5, cu = i & 31;
        int l = l0 - 3 + r;
        ((uint*)&uu.st.rawx[r][0])[cu] =
            (l >= 0) ? ((const uint*)(xb + (size_t)l * 288 + h * 64))[cu] : 0u;
    }
    for (int i = t; i < 67 * 16; i += 256) {
        int r = i >> 4, cu = i & 15;
        int l = l0 - 3 + r;
        ((uint*)&uu.st.rawbc[r][0])[cu] =
            (l >= 0) ? ((const uint*)(xb + (size_t)l * 288 + 256))[cu] : 0u;
    }
    for (int i = t; i < 512; i += 256) {          // K-window pad: cols 16..31
        int r = i >> 3, cc = i & 7;
        ((uint*)&Bb[r][16])[cc] = 0;
        ((uint*)&Cb[r][16])[cc] = 0;
    }
    if (t < 64) {
        float dv = dtbuf[((size_t)(b * 4 + h)) * LL + l0 + t];
        float run = dv * A;
        #pragma unroll
        for (int off = 1; off < 64; off <<= 1) {
            float o = __shfl_up(run, off, 64);
            if (t >= off) run += o;
        }
        dtt[t] = dv;
        laa[t] = run;
        cdecbuf[((size_t)(b * 4 + h)) * LL + l0 + t] = fexp(run);
        float laEnd = __shfl(run, 63, 64);
        ww[t] = dv * fexp(laEnd - run);
    }
    __syncthreads();

    // ---- phase 2: conv + SiLU -> bf16 tiles (vectorized XbT writes) ----
    {
        const int jx = t & 63;
        const int w0 = (t >> 6) * 16;              // 16 consecutive tokens/thread
        const int cx = h * 64 + jx;
        const float4 cwx = *(const float4*)&conv_w[cx * 4];
        const float  cbx = conv_b[cx];
        float r0[19];
        #pragma unroll
        for (int k = 0; k < 19; ++k) r0[k] = bf2f(uu.st.rawx[w0 + k][jx]);
        ushort vv[16];
        #pragma unroll
        for (int k = 0; k < 16; ++k) {
            float v = cbx + r0[k] * cwx.x + r0[k + 1] * cwx.y
                          + r0[k + 2] * cwx.z + r0[k + 3] * cwx.w;
            vv[k] = f2bf(fsilu(v));
        }
        *(bf16x8*)&XbT[jx][w0]     = *(bf16x8*)&vv[0];
        *(bf16x8*)&XbT[jx][w0 + 8] = *(bf16x8*)&vv[8];

        const int jbc = t & 31, cbc = 256 + jbc;
        const float4 cwb = *(const float4*)&conv_w[cbc * 4];
        const float  cbb = conv_b[cbc];
        #pragma unroll
        for (int i = 0; i < 8; ++i) {
            int ss = (t >> 5) + i * 8;
            float v = cbb + bf2f(uu.st.rawbc[ss][jbc]) * cwb.x
                          + bf2f(uu.st.rawbc[ss + 1][jbc]) * cwb.y
                          + bf2f(uu.st.rawbc[ss + 2][jbc]) * cwb.z
                          + bf2f(uu.st.rawbc[ss + 3][jbc]) * cwb.w;
            v = fsilu(v);
            if (jbc < 16) Bb[ss][jbc] = f2bf(v);
            else {
                ushort bv = f2bf(v);
                Cb[ss][jbc - 16] = bv;
                Cpost[((size_t)b * LL + l0 + ss) * DSTATE + (jbc - 16)] = bv;
            }
        }
    }
    __syncthreads();

    const int w = t >> 6, l = t & 63;
    const int fr = l & 15, fq = l >> 4;

    // ---- phase 3: G = C.B^T, mask -> Mb (own rows); BwT; then Y (no barrier) ----
    f32x4 gacc[4];
    {
        bf16x8 ca = *(const bf16x8*)&Cb[w * 16 + fr][fq * 8];
        #pragma unroll
        for (int jt = 0; jt < 4; ++jt) {
            bf16x8 bb = *(const bf16x8*)&Bb[jt * 16 + fr][fq * 8];
            f32x4 z = {0.f, 0.f, 0.f, 0.f};
            gacc[jt] = __builtin_amdgcn_mfma_f32_16x16x32_bf16(ca, bb, z, 0, 0, 0);
        }
    }
    #pragma unroll
    for (int jt = 0; jt < 4; ++jt) {
        int j = jt * 16 + fr;
        float laj = laa[j], dtj = dtt[j];
        #pragma unroll
        for (int r = 0; r < 4; ++r) {
            int i = w * 16 + fq * 4 + r;
            float m = (j <= i) ? gacc[jt][r] * fexp(laa[i] - laj) * dtj : 0.f;
            uu.ssd.Mb[i][j] = f2bf(m);
        }
    }
    #pragma unroll
    for (int i2 = 0; i2 < 4; ++i2) {
        int idx = t + i2 * 256;
        int n = idx & 15, jj = idx >> 4;
        uu.ssd.BwT[n][jj] = f2bf(ww[jj] * bf2f(Bb[jj][n]));
    }

    // Y = M.X (+D skip): wave-private Mb rows + XbT (already barriered) -> no sync
    {
        bf16x8 ma0 = *(const bf16x8*)&uu.ssd.Mb[w * 16 + fr][fq * 8];
        bf16x8 ma1 = *(const bf16x8*)&uu.ssd.Mb[w * 16 + fr][32 + fq * 8];
        #pragma unroll
        for (int pt = 0; pt < 4; ++pt) {
            bf16x8 xb0 = *(const bf16x8*)&XbT[pt * 16 + fr][fq * 8];
            bf16x8 xb1 = *(const bf16x8*)&XbT[pt * 16 + fr][32 + fq * 8];
            f32x4 acc = {0.f, 0.f, 0.f, 0.f};
            acc = __builtin_amdgcn_mfma_f32_16x16x32_bf16(ma0, xb0, acc, 0, 0, 0);
            acc = __builtin_amdgcn_mfma_f32_16x16x32_bf16(ma1, xb1, acc, 0, 0, 0);
            #pragma unroll
            for (int r = 0; r < 4; ++r) {
                int i = w * 16 + fq * 4 + r;          // own rows only
                int p = pt * 16 + fr;
                float xv = bf2f(XbT[p][i]);
                uu.ssd.Mb[i][p] = f2bf(acc[r] + Dh * xv);
            }
        }
    }
    __syncthreads();   // BwT complete (for S) + all waves' Y rows (for y store)

    if (c < 15) {
        bf16x8 xa0 = *(const bf16x8*)&XbT[w * 16 + fr][fq * 8];
        bf16x8 xa1 = *(const bf16x8*)&XbT[w * 16 + fr][32 + fq * 8];
        bf16x8 bw0 = *(const bf16x8*)&uu.ssd.BwT[fr][fq * 8];
        bf16x8 bw1 = *(const bf16x8*)&uu.ssd.BwT[fr][32 + fq * 8];
        f32x4 acc = {0.f, 0.f, 0.f, 0.f};
        acc = __builtin_amdgcn_mfma_f32_16x16x32_bf16(xa0, bw0, acc, 0, 0, 0);
        acc = __builtin_amdgcn_mfma_f32_16x16x32_bf16(xa1, bw1, acc, 0, 0, 0);
        float* Sdst = h0buf + (((size_t)(b * 4 + h)) * NCH + (c + 1)) * 1024;
        #pragma unroll
        for (int r = 0; r < 4; ++r) {
            int p = w * 16 + fq * 4 + r;
            Sdst[p * 16 + fr] = acc[r];
        }
    }

    {
        ushort* ybase = y + ((size_t)b * LL + l0) * DINN + h * 64;
        #pragma unroll
        for (int ii = 0; ii < 2; ++ii) {
            int idx = t + ii * 256;
            int row = idx >> 3, c8 = (idx & 7) * 8;
            *(uint4*)&ybase[(size_t)row * DINN + c8] = *(const uint4*)&uu.ssd.Mb[row][c8];
        }
    }
}

// ---------------- K3b: chunk-level scan (16 chunks) ----------------
__global__ __launch_bounds__(256) void k3b_chunkscan(
        float* __restrict__ h0buf, const float* __restrict__ cdecbuf) {
    const int bh = blockIdx.x;
    const int t = threadIdx.x;
    float* base = h0buf + (size_t)bh * NCH * 1024;
    const float* cd = cdecbuf + (size_t)bh * LL;
    float4 run = {0.f, 0.f, 0.f, 0.f};
    *(float4*)&base[(size_t)t * 4] = run;
    #pragma unroll
    for (int c = 1; c < NCH; ++c) {
        float P = cd[c * CS - 1];
        float4 S = *(float4*)&base[(size_t)c * 1024 + t * 4];
        run.x = fmaf(run.x, P, S.x);
        run.y = fmaf(run.y, P, S.y);
        run.z = fmaf(run.z, P, S.z);
        run.w = fmaf(run.w, P, S.w);
        *(float4*)&base[(size_t)c * 1024 + t * 4] = run;
    }
}

// ------- K4: M=64 tile; correction (H regs) + gate + RMSNorm + out_proj -------
__global__ __launch_bounds__(256) void k4_out(
        const ushort* __restrict__ ybf, const ushort* __restrict__ zbuf,
        const float* __restrict__ ngw, const ushort* __restrict__ Wob,
        const float* __restrict__ x, const float* __restrict__ h0buf,
        const float* __restrict__ cdecbuf, const ushort* __restrict__ Cpost,
        float* __restrict__ out) {
    __shared__ float Cs[64][16];
    __shared__ float cds[64][4];
    __shared__ ushort gb[64][264];
    const int t = threadIdx.x;
    const int m0 = blockIdx.x * 64;
    const int b  = m0 >> 10;
    const int l0 = m0 & 1023;
    const int ck = l0 >> 6;
    const ushort* yb = ybf + (size_t)m0 * DINN;
    const ushort* zb = zbuf + (size_t)m0 * DINN;

    {
        int r = t >> 2, n0 = (t & 3) * 4;
        ushort4 cu4 = *(const ushort4*)&Cpost[((size_t)b * LL + l0 + r) * DSTATE + n0];
        Cs[r][n0 + 0] = bf2f(cu4.x);
        Cs[r][n0 + 1] = bf2f(cu4.y);
        Cs[r][n0 + 2] = bf2f(cu4.z);
        Cs[r][n0 + 3] = bf2f(cu4.w);
        int hh2 = t & 3;
        cds[r][hh2] = cdecbuf[((size_t)(b * 4 + hh2)) * LL + l0 + r];
    }

    const int ch4 = (t & 63) * 4;
    const int hh  = ch4 >> 6;
    const int p0  = ch4 & 63;
    const float* hbase = h0buf + (((size_t)(b * 4 + hh)) * NCH + ck) * 1024 + p0 * 16;
    float4 H[4][4];
    #pragma unroll
    for (int k = 0; k < 4; ++k)
        #pragma unroll
        for (int n4 = 0; n4 < 4; ++n4)
            H[k][n4] = *(const float4*)&hbase[k * 16 + n4 * 4];
    __syncthreads();

    const float4 ng4 = *(const float4*)&ngw[ch4];

    #pragma unroll
    for (int i = 0; i < 16; ++i) {
        int row = i * 4 + (t >> 6);
        ushort4 yu = *(const ushort4*)&yb[(size_t)row * DINN + ch4];
        ushort4 zu = *(const ushort4*)&zb[(size_t)row * DINN + ch4];
        float4 yv = { bf2f(yu.x), bf2f(yu.y), bf2f(yu.z), bf2f(yu.w) };
        float4 zv = { bf2f(zu.x), bf2f(zu.y), bf2f(zu.z), bf2f(zu.w) };  // silu(z)
        float4 C0 = *(const float4*)&Cs[row][0];
        float4 C1 = *(const float4*)&Cs[row][4];
        float4 C2 = *(const float4*)&Cs[row][8];
        float4 C3 = *(const float4*)&Cs[row][12];
        float cdv = cds[row][hh];
        float corr[4];
        #pragma unroll
        for (int k = 0; k < 4; ++k) {
            float s = H[k][0].x * C0.x + H[k][0].y * C0.y + H[k][0].z * C0.z + H[k][0].w * C0.w;
            s += H[k][1].x * C1.x + H[k][1].y * C1.y + H[k][1].z * C1.z + H[k][1].w * C1.w;
            s += H[k][2].x * C2.x + H[k][2].y * C2.y + H[k][2].z * C2.z + H[k][2].w * C2.w;
            s += H[k][3].x * C3.x + H[k][3].y * C3.y + H[k][3].z * C3.z + H[k][3].w * C3.w;
            corr[k] = s * cdv;
        }
        float4 gv;
        gv.x = (yv.x + corr[0]) * zv.x;
        gv.y = (yv.y + corr[1]) * zv.y;
        gv.z = (yv.z + corr[2]) * zv.z;
        gv.w = (yv.w + corr[3]) * zv.w;
        float s = gv.x * gv.x + gv.y * gv.y + gv.z * gv.z + gv.w * gv.w;
        s += __shfl_xor(s, 1);  s += __shfl_xor(s, 2);  s += __shfl_xor(s, 4);
        s += __shfl_xor(s, 8);  s += __shfl_xor(s, 16); s += __shfl_xor(s, 32);
        float rs = rsqrtf(s * (1.f / 256.f) + EPSF);
        ushort4 o;
        o.x = f2bf(gv.x * rs * ng4.x);
        o.y = f2bf(gv.y * rs * ng4.y);
        o.z = f2bf(gv.z * rs * ng4.z);
        o.w = f2bf(gv.w * rs * ng4.w);
        *(ushort4*)&gb[row][ch4] = o;
    }
    __syncthreads();

    const int w = t >> 6, l = t & 63;
    const int j = l & 15, kb = (l >> 4) * 8;
    bf16x8 bf[8];
    #pragma unroll
    for (int ks = 0; ks < 8; ++ks)
        bf[ks] = *(const bf16x8*)&Wob[(size_t)(16 * w + j) * DINN + ks * 32 + kb];
    #pragma unroll
    for (int mt = 0; mt < 4; ++mt) {
        f32x4 acc = {0.f, 0.f, 0.f, 0.f};
        #pragma unroll
        for (int ks = 0; ks < 8; ++ks) {
            bf16x8 af = *(const bf16x8*)&gb[mt * 16 + j][ks * 32 + kb];
            acc = __builtin_amdgcn_mfma_f32_16x16x32_bf16(af, bf[ks], acc, 0, 0, 0);
        }
        #pragma unroll
        for (int r = 0; r < 4; ++r) {
            size_t row = (size_t)m0 + mt * 16 + (l >> 4) * 4 + r;
            size_t oidx = row * 64 + 16 * w + j;
            out[oidx] = acc[r] + 2.f * x[oidx];
        }
    }
}

extern "C" void kernel_launch(void* const* d_in, const int* in_sizes, int n_in,
                              void* d_out, int out_size, void* d_ws, size_t ws_size,
                              hipStream_t stream) {
    const float* x          = (const float*)d_in[0];
    const float* in_proj_w  = (const float*)d_in[1];
    const float* conv_w     = (const float*)d_in[2];
    const float* conv_b     = (const float*)d_in[3];
    const float* dt_bias    = (const float*)d_in[4];
    const float* A_log      = (const float*)d_in[5];
    const float* D          = (const float*)d_in[6];
    const float* norm_gate  = (const float*)d_in[7];
    const float* out_proj_w = (const float*)d_in[8];
    const float* block_norm = (const float*)d_in[9];
    float* out = (float*)d_out;

    float* h0b   = (float*)d_ws;                               //  2,097,152 f32
    float* cdec  = h0b  + (size_t)BB * NHEADS * NCH * 1024;    //    131,072 f32
    float* dtb   = cdec + (size_t)BB * NHEADS * LL;            //    131,072 f32
    ushort* Cp   = (ushort*)(dtb + (size_t)BB * NHEADS * LL);  //    524,288 us
    ushort* ybf  = Cp   + (size_t)BB * LL * DSTATE;            //  8,388,608 us
    ushort* zbuf = ybf  + (size_t)BB * LL * DINN;              //  8,388,608 us
    ushort* xbc  = zbuf + (size_t)BB * LL * DINN;              //  9,437,184 us
    ushort* Wb   = xbc  + (size_t)BB * LL * 288;               //     35,072 us
    ushort* Wob  = Wb   + (size_t)DINPROJ * 64;                //     16,384 us

    kwcvt<<<201, 256, 0, stream>>>(in_proj_w, out_proj_w, Wb, Wob);
    k1_mfma<<<1024, 256, 0, stream>>>(x, Wb, block_norm, in_proj_w, dt_bias, zbuf, xbc, dtb);
    k3a_ssd<<<2048, 256, 0, stream>>>(xbc, dtb, conv_w, conv_b, A_log, D, ybf, h0b, cdec, Cp);
    k3b_chunkscan<<<128, 256, 0, stream>>>(h0b, cdec);
    k4_out<<<512, 256, 0, stream>>>(ybf, zbuf, norm_gate, Wob, x, h0b, cdec, Cp, out);
}

// Round 13
// 68.977 us; speedup vs baseline: 1.6313x; 1.0195x over previous
//
#include <hip/hip_runtime.h>
#include <math.h>

#define BB 32
#define LL 1024
#define DIMM 64
#define DINN 256
#define NHEADS 4
#define DSTATE 16
#define DINPROJ 548
#define EPSF 1e-5f
#define NCH 16    // chunks per sequence
#define CS 64     // chunk size

typedef __attribute__((ext_vector_type(8))) short bf16x8;
typedef __attribute__((ext_vector_type(4))) float f32x4;

__device__ inline ushort f2bf(float f) {
    union { float f; unsigned u; } v; v.f = f;
    unsigned r = (v.u + 0x7FFFu + ((v.u >> 16) & 1u)) >> 16;
    return (ushort)r;
}
__device__ inline float bf2f(ushort u) {
    union { float f; unsigned u; } v; v.u = ((unsigned)u) << 16; return v.f;
}
__device__ inline float fexp(float v) { return __expf(v); }
__device__ inline float fsilu(float v) {
    return v * __builtin_amdgcn_rcpf(1.f + __expf(-v));
}

// ---------------- K0: convert weights to bf16 ----------------
__global__ __launch_bounds__(256) void kwcvt(
        const float* __restrict__ Win, const float* __restrict__ Wout,
        ushort* __restrict__ Wb, ushort* __restrict__ Wob) {
    int i = blockIdx.x * 256 + threadIdx.x;
    if (i < DINPROJ * 64) Wb[i] = f2bf(Win[i]);
    else if (i < DINPROJ * 64 + 64 * DINN) {
        int j = i - DINPROJ * 64;
        Wob[j] = f2bf(Wout[j]);
    }
}

// -- K1: RMSNorm + in_proj xBC-only (bf16 MFMA) + fp32 dt + coalesced stores --
__global__ __launch_bounds__(256) void k1_mfma(
        const float* __restrict__ x, const ushort* __restrict__ Wb,
        const float* __restrict__ bnw, const float* __restrict__ Wfp,
        const float* __restrict__ dt_bias,
        ushort* __restrict__ xbcbuf, float* __restrict__ dtbuf) {
    __shared__ __align__(16) union {
        struct { float u[32][68]; float wdt[4][68]; } a;   // 9.8 KB
        ushort ob[32][296];                                 // 18.9 KB
    } s;
    __shared__ float rstd[32];
    const int t = threadIdx.x;
    const int m0 = blockIdx.x * 32;
    const int b = m0 >> 10;
    const int lbase = m0 & 1023;

    const float* xrow = x + (size_t)m0 * 64;
    #pragma unroll
    for (int i = 0; i < 2; ++i) {
        int idx = t + i * 256;
        float4 v = ((const float4*)xrow)[idx];
        *(float4*)&s.a.u[idx >> 4][(idx & 15) * 4] = v;
    }
    s.a.wdt[t >> 6][t & 63] = Wfp[(size_t)(544 + (t >> 6)) * 64 + (t & 63)] * bnw[t & 63];
    __syncthreads();
    {
        int row = t >> 3, part = t & 7;
        float ss = 0.f;
        #pragma unroll
        for (int j = 0; j < 8; ++j) { float v = s.a.u[row][part * 8 + j]; ss = fmaf(v, v, ss); }
        ss += __shfl_xor(ss, 1); ss += __shfl_xor(ss, 2); ss += __shfl_xor(ss, 4);
        if (part == 0) rstd[row] = rsqrtf(ss * (1.f / 64.f) + EPSF);
    }
    __syncthreads();

    const int w = t >> 6, l = t & 63;
    const int a = l & 15, kb = (l >> 4) * 8;

    float4 bw[2][2];
    bw[0][0] = *(const float4*)&bnw[kb];
    bw[0][1] = *(const float4*)&bnw[kb + 4];
    bw[1][0] = *(const float4*)&bnw[32 + kb];
    bw[1][1] = *(const float4*)&bnw[32 + kb + 4];

    bf16x8 af[2][2];
    #pragma unroll
    for (int mt = 0; mt < 2; ++mt) {
        float rs = rstd[mt * 16 + a];
        #pragma unroll
        for (int kk = 0; kk < 2; ++kk) {
            float4 v0 = *(const float4*)&s.a.u[mt * 16 + a][kk * 32 + kb];
            float4 v1 = *(const float4*)&s.a.u[mt * 16 + a][kk * 32 + kb + 4];
            ushort* p = (ushort*)&af[mt][kk];
            p[0] = f2bf(v0.x * rs * bw[kk][0].x);
            p[1] = f2bf(v0.y * rs * bw[kk][0].y);
            p[2] = f2bf(v0.z * rs * bw[kk][0].z);
            p[3] = f2bf(v0.w * rs * bw[kk][0].w);
            p[4] = f2bf(v1.x * rs * bw[kk][1].x);
            p[5] = f2bf(v1.y * rs * bw[kk][1].y);
            p[6] = f2bf(v1.z * rs * bw[kk][1].z);
            p[7] = f2bf(v1.w * rs * bw[kk][1].w);
        }
    }

    if (t < 128) {
        int row = t >> 2, h = t & 3;
        const float* ur = s.a.u[row];
        const float* wr = s.a.wdt[h];
        float sd = 0.f;
        #pragma unroll
        for (int k4 = 0; k4 < 16; ++k4) {
            float4 uv = *(const float4*)&ur[k4 * 4];
            float4 wv = *(const float4*)&wr[k4 * 4];
            sd = fmaf(uv.x, wv.x, sd); sd = fmaf(uv.y, wv.y, sd);
            sd = fmaf(uv.z, wv.z, sd); sd = fmaf(uv.w, wv.w, sd);
        }
        sd = sd * rstd[row] + dt_bias[h];
        sd = fmaxf(sd, 0.f) + log1pf(expf(-fabsf(sd)));   // keep precise
        dtbuf[((size_t)(b * 4 + h)) * LL + lbase + row] = sd;
    }
    __syncthreads();   // u/wdt dead; ob may now be written

    // xBC columns only: nt = 16..33
    for (int nt = 16 + w; nt < 34; nt += 4) {
        const ushort* wbp = Wb + (size_t)(nt * 16 + a) * 64 + kb;
        bf16x8 b0 = *(const bf16x8*)wbp;
        bf16x8 b1 = *(const bf16x8*)(wbp + 32);
        #pragma unroll
        for (int mt = 0; mt < 2; ++mt) {
            f32x4 acc = {0.f, 0.f, 0.f, 0.f};
            acc = __builtin_amdgcn_mfma_f32_16x16x32_bf16(af[mt][0], b0, acc, 0, 0, 0);
            acc = __builtin_amdgcn_mfma_f32_16x16x32_bf16(af[mt][1], b1, acc, 0, 0, 0);
            int row0 = mt * 16 + (l >> 4) * 4;
            int col = nt * 16 + a - 256;
            #pragma unroll
            for (int r = 0; r < 4; ++r) s.ob[row0 + r][col] = f2bf(acc[r]);
        }
    }
    __syncthreads();

    for (int i = t; i < 1152; i += 256) {           // 32 rows x 36 chunks
        int row = i / 36, c8 = (i % 36) * 8;
        *(uint4*)&xbcbuf[(size_t)(m0 + row) * 288 + c8] = *(const uint4*)&s.ob[row][c8];
    }
}

// ---------------- K3a: SSD chunked scan via MFMA (bf16 in/out) ----------------
__global__ __launch_bounds__(256) void k3a_ssd(
        const ushort* __restrict__ xbcbuf, const float* __restrict__ dtbuf,
        const float* __restrict__ conv_w, const float* __restrict__ conv_b,
        const float* __restrict__ A_log, const float* __restrict__ Dp,
        ushort* __restrict__ y, float* __restrict__ h0buf,
        float* __restrict__ cdecbuf, ushort* __restrict__ Cpost) {
    const int bid = blockIdx.x;
    const int c = bid & 15, h = (bid >> 4) & 3, b = bid >> 6;
    const int t = threadIdx.x;

    __shared__ __align__(16) union {
        struct { ushort rawx[67][64]; ushort rawbc[67][32]; } st;
        struct { ushort Mb[64][72]; ushort BwT[16][72]; } ssd;
    } uu;
    __shared__ ushort XbT[64][72];
    __shared__ ushort Bb[64][40];
    __shared__ ushort Cb[64][40];
    __shared__ float dtt[64], laa[64], ww[64];

    const float A  = -expf(A_log[h]);
    const float Dh = Dp[h];
    const int l0 = c * CS;
    const ushort* xb = xbcbuf + (size_t)b * LL * 288;

    for (int i = t; i < 67 * 32; i += 256) {
        int r = i >> 5, cu = i & 31;
        int l = l0 - 3 + r;
        ((uint*)&uu.st.rawx[r][0])[cu] =
            (l >= 0) ? ((const uint*)(xb + (size_t)l * 288 + h * 64))[cu] : 0u;
    }
    for (int i = t; i < 67 * 16; i += 256) {
        int r = i >> 4, cu = i & 15;
        int l = l0 - 3 + r;
        ((uint*)&uu.st.rawbc[r][0])[cu] =
            (l >= 0) ? ((const uint*)(xb + (size_t)l * 288 + 256))[cu] : 0u;
    }
    for (int i = t; i < 512; i += 256) {
        int r = i >> 3, cc = i & 7;
        ((uint*)&Bb[r][16])[cc] = 0;
        ((uint*)&Cb[r][16])[cc] = 0;
    }
    if (t < 64) {
        float dv = dtbuf[((size_t)(b * 4 + h)) * LL + l0 + t];
        float run = dv * A;
        #pragma unroll
        for (int off = 1; off < 64; off <<= 1) {
            float o = __shfl_up(run, off, 64);
            if (t >= off) run += o;
        }
        dtt[t] = dv;
        laa[t] = run;
        cdecbuf[((size_t)(b * 4 + h)) * LL + l0 + t] = fexp(run);
        float laEnd = __shfl(run, 63, 64);
        ww[t] = dv * fexp(laEnd - run);
    }
    __syncthreads();

    {
        const int jx = t & 63;
        const int w0 = (t >> 6) * 16;
        const int cx = h * 64 + jx;
        const float4 cwx = *(const float4*)&conv_w[cx * 4];
        const float  cbx = conv_b[cx];
        float r0[19];
        #pragma unroll
        for (int k = 0; k < 19; ++k) r0[k] = bf2f(uu.st.rawx[w0 + k][jx]);
        ushort vv[16];
        #pragma unroll
        for (int k = 0; k < 16; ++k) {
            float v = cbx + r0[k] * cwx.x + r0[k + 1] * cwx.y
                          + r0[k + 2] * cwx.z + r0[k + 3] * cwx.w;
            vv[k] = f2bf(fsilu(v));
        }
        *(bf16x8*)&XbT[jx][w0]     = *(bf16x8*)&vv[0];
        *(bf16x8*)&XbT[jx][w0 + 8] = *(bf16x8*)&vv[8];

        const int jbc = t & 31, cbc = 256 + jbc;
        const float4 cwb = *(const float4*)&conv_w[cbc * 4];
        const float  cbb = conv_b[cbc];
        #pragma unroll
        for (int i = 0; i < 8; ++i) {
            int ss = (t >> 5) + i * 8;
            float v = cbb + bf2f(uu.st.rawbc[ss][jbc]) * cwb.x
                          + bf2f(uu.st.rawbc[ss + 1][jbc]) * cwb.y
                          + bf2f(uu.st.rawbc[ss + 2][jbc]) * cwb.z
                          + bf2f(uu.st.rawbc[ss + 3][jbc]) * cwb.w;
            v = fsilu(v);
            if (jbc < 16) Bb[ss][jbc] = f2bf(v);
            else {
                ushort bv = f2bf(v);
                Cb[ss][jbc - 16] = bv;
                Cpost[((size_t)b * LL + l0 + ss) * DSTATE + (jbc - 16)] = bv;
            }
        }
    }
    __syncthreads();

    const int w = t >> 6, l = t & 63;
    const int fr = l & 15, fq = l >> 4;

    f32x4 gacc[4];
    {
        bf16x8 ca = *(const bf16x8*)&Cb[w * 16 + fr][fq * 8];
        #pragma unroll
        for (int jt = 0; jt < 4; ++jt) {
            bf16x8 bb = *(const bf16x8*)&Bb[jt * 16 + fr][fq * 8];
            f32x4 z = {0.f, 0.f, 0.f, 0.f};
            gacc[jt] = __builtin_amdgcn_mfma_f32_16x16x32_bf16(ca, bb, z, 0, 0, 0);
        }
    }
    #pragma unroll
    for (int jt = 0; jt < 4; ++jt) {
        int j = jt * 16 + fr;
        float laj = laa[j], dtj = dtt[j];
        #pragma unroll
        for (int r = 0; r < 4; ++r) {
            int i = w * 16 + fq * 4 + r;
            float m = (j <= i) ? gacc[jt][r] * fexp(laa[i] - laj) * dtj : 0.f;
            uu.ssd.Mb[i][j] = f2bf(m);
        }
    }
    #pragma unroll
    for (int i2 = 0; i2 < 4; ++i2) {
        int idx = t + i2 * 256;
        int n = idx & 15, jj = idx >> 4;
        uu.ssd.BwT[n][jj] = f2bf(ww[jj] * bf2f(Bb[jj][n]));
    }

    {
        bf16x8 ma0 = *(const bf16x8*)&uu.ssd.Mb[w * 16 + fr][fq * 8];
        bf16x8 ma1 = *(const bf16x8*)&uu.ssd.Mb[w * 16 + fr][32 + fq * 8];
        #pragma unroll
        for (int pt = 0; pt < 4; ++pt) {
            bf16x8 xb0 = *(const bf16x8*)&XbT[pt * 16 + fr][fq * 8];
            bf16x8 xb1 = *(const bf16x8*)&XbT[pt * 16 + fr][32 + fq * 8];
            f32x4 acc = {0.f, 0.f, 0.f, 0.f};
            acc = __builtin_amdgcn_mfma_f32_16x16x32_bf16(ma0, xb0, acc, 0, 0, 0);
            acc = __builtin_amdgcn_mfma_f32_16x16x32_bf16(ma1, xb1, acc, 0, 0, 0);
            #pragma unroll
            for (int r = 0; r < 4; ++r) {
                int i = w * 16 + fq * 4 + r;
                int p = pt * 16 + fr;
                float xv = bf2f(XbT[p][i]);
                uu.ssd.Mb[i][p] = f2bf(acc[r] + Dh * xv);
            }
        }
    }
    __syncthreads();

    if (c < 15) {
        bf16x8 xa0 = *(const bf16x8*)&XbT[w * 16 + fr][fq * 8];
        bf16x8 xa1 = *(const bf16x8*)&XbT[w * 16 + fr][32 + fq * 8];
        bf16x8 bw0 = *(const bf16x8*)&uu.ssd.BwT[fr][fq * 8];
        bf16x8 bw1 = *(const bf16x8*)&uu.ssd.BwT[fr][32 + fq * 8];
        f32x4 acc = {0.f, 0.f, 0.f, 0.f};
        acc = __builtin_amdgcn_mfma_f32_16x16x32_bf16(xa0, bw0, acc, 0, 0, 0);
        acc = __builtin_amdgcn_mfma_f32_16x16x32_bf16(xa1, bw1, acc, 0, 0, 0);
        float* Sdst = h0buf + (((size_t)(b * 4 + h)) * NCH + (c + 1)) * 1024;
        #pragma unroll
        for (int r = 0; r < 4; ++r) {
            int p = w * 16 + fq * 4 + r;
            Sdst[p * 16 + fr] = acc[r];
        }
    }

    {
        ushort* ybase = y + ((size_t)b * LL + l0) * DINN + h * 64;
        #pragma unroll
        for (int ii = 0; ii < 2; ++ii) {
            int idx = t + ii * 256;
            int row = idx >> 3, c8 = (idx & 7) * 8;
            *(uint4*)&ybase[(size_t)row * DINN + c8] = *(const uint4*)&uu.ssd.Mb[row][c8];
        }
    }
}

// ---------------- K3b: chunk-level scan (16 chunks) ----------------
__global__ __launch_bounds__(256) void k3b_chunkscan(
        float* __restrict__ h0buf, const float* __restrict__ cdecbuf) {
    const int bh = blockIdx.x;
    const int t = threadIdx.x;
    float* base = h0buf + (size_t)bh * NCH * 1024;
    const float* cd = cdecbuf + (size_t)bh * LL;
    float4 run = {0.f, 0.f, 0.f, 0.f};
    *(float4*)&base[(size_t)t * 4] = run;
    #pragma unroll
    for (int c = 1; c < NCH; ++c) {
        float P = cd[c * CS - 1];
        float4 S = *(float4*)&base[(size_t)c * 1024 + t * 4];
        run.x = fmaf(run.x, P, S.x);
        run.y = fmaf(run.y, P, S.y);
        run.z = fmaf(run.z, P, S.z);
        run.w = fmaf(run.w, P, S.w);
        *(float4*)&base[(size_t)c * 1024 + t * 4] = run;
    }
}

// ---- K4: z recomputed via MFMA + correction + gate + RMSNorm + out_proj ----
// grid 512 = (b, chunk); block 256 = 4 waves
__global__ __launch_bounds__(256) void k4_out(
        const ushort* __restrict__ ybf, const float* __restrict__ ngw,
        const ushort* __restrict__ Wob, const ushort* __restrict__ Wb,
        const float* __restrict__ bnw, const float* __restrict__ x,
        const float* __restrict__ h0buf, const float* __restrict__ cdecbuf,
        const ushort* __restrict__ Cpost, float* __restrict__ out) {
    __shared__ __align__(16) union {
        float u[64][68];        // 17.4 KB (phase A)
        ushort zg[64][264];     // 33.8 KB (silu(z) then g)
    } s;
    __shared__ float Cs[64][16];
    __shared__ float cds[64][4];
    __shared__ float rstd[64];
    const int t = threadIdx.x;
    const int m0 = blockIdx.x * 64;
    const int b  = m0 >> 10;
    const int l0 = m0 & 1023;
    const int ck = l0 >> 6;
    const ushort* yb = ybf + (size_t)m0 * DINN;

    // H register loads (L2-resident) issued first
    const int ch4 = (t & 63) * 4;
    const int hh  = ch4 >> 6;
    const int p0  = ch4 & 63;
    const float* hbase = h0buf + (((size_t)(b * 4 + hh)) * NCH + ck) * 1024 + p0 * 16;
    float4 H[4][4];
    #pragma unroll
    for (int k = 0; k < 4; ++k)
        #pragma unroll
        for (int n4 = 0; n4 < 4; ++n4)
            H[k][n4] = *(const float4*)&hbase[k * 16 + n4 * 4];

    // stage x tile (64 x 64 fp32), C, cdec
    const float* xrow = x + (size_t)m0 * 64;
    #pragma unroll
    for (int i = 0; i < 4; ++i) {
        int idx = t + i * 256;
        float4 v = ((const float4*)xrow)[idx];
        *(float4*)&s.u[idx >> 4][(idx & 15) * 4] = v;
    }
    {
        int r = t >> 2, n0 = (t & 3) * 4;
        ushort4 cu4 = *(const ushort4*)&Cpost[((size_t)b * LL + l0 + r) * DSTATE + n0];
        Cs[r][n0 + 0] = bf2f(cu4.x);
        Cs[r][n0 + 1] = bf2f(cu4.y);
        Cs[r][n0 + 2] = bf2f(cu4.z);
        Cs[r][n0 + 3] = bf2f(cu4.w);
        int hh2 = t & 3;
        cds[r][hh2] = cdecbuf[((size_t)(b * 4 + hh2)) * LL + l0 + r];
    }
    __syncthreads();

    // rstd per row (4 threads/row x 16 elems)
    {
        int row = t >> 2, part = t & 3;
        float ss = 0.f;
        #pragma unroll
        for (int j = 0; j < 16; ++j) { float v = s.u[row][part * 16 + j]; ss = fmaf(v, v, ss); }
        ss += __shfl_xor(ss, 1); ss += __shfl_xor(ss, 2);
        if (part == 0) rstd[row] = rsqrtf(ss * (1.f / 64.f) + EPSF);
    }
    __syncthreads();

    // build bf16 A-fragments (RMSNorm + block_norm folded)
    const int w = t >> 6, l = t & 63;
    const int a = l & 15, kb = (l >> 4) * 8;
    float4 bw[2][2];
    bw[0][0] = *(const float4*)&bnw[kb];
    bw[0][1] = *(const float4*)&bnw[kb + 4];
    bw[1][0] = *(const float4*)&bnw[32 + kb];
    bw[1][1] = *(const float4*)&bnw[32 + kb + 4];
    bf16x8 af[4][2];
    #pragma unroll
    for (int mt = 0; mt < 4; ++mt) {
        float rs = rstd[mt * 16 + a];
        #pragma unroll
        for (int kk = 0; kk < 2; ++kk) {
            float4 v0 = *(const float4*)&s.u[mt * 16 + a][kk * 32 + kb];
            float4 v1 = *(const float4*)&s.u[mt * 16 + a][kk * 32 + kb + 4];
            ushort* p = (ushort*)&af[mt][kk];
            p[0] = f2bf(v0.x * rs * bw[kk][0].x);
            p[1] = f2bf(v0.y * rs * bw[kk][0].y);
            p[2] = f2bf(v0.z * rs * bw[kk][0].z);
            p[3] = f2bf(v0.w * rs * bw[kk][0].w);
            p[4] = f2bf(v1.x * rs * bw[kk][1].x);
            p[5] = f2bf(v1.y * rs * bw[kk][1].y);
            p[6] = f2bf(v1.z * rs * bw[kk][1].z);
            p[7] = f2bf(v1.w * rs * bw[kk][1].w);
        }
    }
    __syncthreads();   // u dead -> zg writes allowed

    // z-GEMM: wave w covers cols [w*64, w*64+64); store silu(z)
    #pragma unroll
    for (int ct4 = 0; ct4 < 4; ++ct4) {
        int ct = w * 4 + ct4;
        const ushort* wbp = Wb + (size_t)(ct * 16 + a) * 64 + kb;
        bf16x8 b0 = *(const bf16x8*)wbp;
        bf16x8 b1 = *(const bf16x8*)(wbp + 32);
        #pragma unroll
        for (int mt = 0; mt < 4; ++mt) {
            f32x4 acc = {0.f, 0.f, 0.f, 0.f};
            acc = __builtin_amdgcn_mfma_f32_16x16x32_bf16(af[mt][0], b0, acc, 0, 0, 0);
            acc = __builtin_amdgcn_mfma_f32_16x16x32_bf16(af[mt][1], b1, acc, 0, 0, 0);
            int row0 = mt * 16 + (l >> 4) * 4;
            int col = ct * 16 + a;
            #pragma unroll
            for (int r = 0; r < 4; ++r) s.zg[row0 + r][col] = f2bf(fsilu(acc[r]));
        }
    }
    __syncthreads();

    const float4 ng4 = *(const float4*)&ngw[ch4];

    // gate + correction + RMSNorm; in-place zg -> g
    #pragma unroll
    for (int i = 0; i < 16; ++i) {
        int row = i * 4 + (t >> 6);
        ushort4 yu = *(const ushort4*)&yb[(size_t)row * DINN + ch4];
        ushort4 zu = *(const ushort4*)&s.zg[row][ch4];
        float4 yv = { bf2f(yu.x), bf2f(yu.y), bf2f(yu.z), bf2f(yu.w) };
        float4 zv = { bf2f(zu.x), bf2f(zu.y), bf2f(zu.z), bf2f(zu.w) };  // silu(z)
        float4 C0 = *(const float4*)&Cs[row][0];
        float4 C1 = *(const float4*)&Cs[row][4];
        float4 C2 = *(const float4*)&Cs[row][8];
        float4 C3 = *(const float4*)&Cs[row][12];
        float cdv = cds[row][hh];
        float corr[4];
        #pragma unroll
        for (int k = 0; k < 4; ++k) {
            float sc = H[k][0].x * C0.x + H[k][0].y * C0.y + H[k][0].z * C0.z + H[k][0].w * C0.w;
            sc += H[k][1].x * C1.x + H[k][1].y * C1.y + H[k][1].z * C1.z + H[k][1].w * C1.w;
            sc += H[k][2].x * C2.x + H[k][2].y * C2.y + H[k][2].z * C2.z + H[k][2].w * C2.w;
            sc += H[k][3].x * C3.x + H[k][3].y * C3.y + H[k][3].z * C3.z + H[k][3].w * C3.w;
            corr[k] = sc * cdv;
        }
        float4 gv;
        gv.x = (yv.x + corr[0]) * zv.x;
        gv.y = (yv.y + corr[1]) * zv.y;
        gv.z = (yv.z + corr[2]) * zv.z;
        gv.w = (yv.w + corr[3]) * zv.w;
        float sq = gv.x * gv.x + gv.y * gv.y + gv.z * gv.z + gv.w * gv.w;
        sq += __shfl_xor(sq, 1);  sq += __shfl_xor(sq, 2);  sq += __shfl_xor(sq, 4);
        sq += __shfl_xor(sq, 8);  sq += __shfl_xor(sq, 16); sq += __shfl_xor(sq, 32);
        float rs = rsqrtf(sq * (1.f / 256.f) + EPSF);
        ushort4 o;
        o.x = f2bf(gv.x * rs * ng4.x);
        o.y = f2bf(gv.y * rs * ng4.y);
        o.z = f2bf(gv.z * rs * ng4.z);
        o.w = f2bf(gv.w * rs * ng4.w);
        *(ushort4*)&s.zg[row][ch4] = o;
    }
    __syncthreads();

    // out_proj
    const int j = l & 15;
    bf16x8 bf[8];
    #pragma unroll
    for (int ks = 0; ks < 8; ++ks)
        bf[ks] = *(const bf16x8*)&Wob[(size_t)(16 * w + j) * DINN + ks * 32 + kb];
    #pragma unroll
    for (int mt = 0; mt < 4; ++mt) {
        f32x4 acc = {0.f, 0.f, 0.f, 0.f};
        #pragma unroll
        for (int ks = 0; ks < 8; ++ks) {
            bf16x8 ag = *(const bf16x8*)&s.zg[mt * 16 + j][ks * 32 + kb];
            acc = __builtin_amdgcn_mfma_f32_16x16x32_bf16(ag, bf[ks], acc, 0, 0, 0);
        }
        #pragma unroll
        for (int r = 0; r < 4; ++r) {
            size_t row = (size_t)m0 + mt * 16 + (l >> 4) * 4 + r;
            size_t oidx = row * 64 + 16 * w + j;
            out[oidx] = acc[r] + 2.f * x[oidx];
        }
    }
}

extern "C" void kernel_launch(void* const* d_in, const int* in_sizes, int n_in,
                              void* d_out, int out_size, void* d_ws, size_t ws_size,
                              hipStream_t stream) {
    const float* x          = (const float*)d_in[0];
    const float* in_proj_w  = (const float*)d_in[1];
    const float* conv_w     = (const float*)d_in[2];
    const float* conv_b     = (const float*)d_in[3];
    const float* dt_bias    = (const float*)d_in[4];
    const float* A_log      = (const float*)d_in[5];
    const float* D          = (const float*)d_in[6];
    const float* norm_gate  = (const float*)d_in[7];
    const float* out_proj_w = (const float*)d_in[8];
    const float* block_norm = (const float*)d_in[9];
    float* out = (float*)d_out;

    float* h0b   = (float*)d_ws;                               //  2,097,152 f32
    float* cdec  = h0b  + (size_t)BB * NHEADS * NCH * 1024;    //    131,072 f32
    float* dtb   = cdec + (size_t)BB * NHEADS * LL;            //    131,072 f32
    ushort* Cp   = (ushort*)(dtb + (size_t)BB * NHEADS * LL);  //    524,288 us
    ushort* ybf  = Cp   + (size_t)BB * LL * DSTATE;            //  8,388,608 us
    ushort* xbc  = ybf  + (size_t)BB * LL * DINN;              //  9,437,184 us
    ushort* Wb   = xbc  + (size_t)BB * LL * 288;               //     35,072 us
    ushort* Wob  = Wb   + (size_t)DINPROJ * 64;                //     16,384 us

    kwcvt<<<201, 256, 0, stream>>>(in_proj_w, out_proj_w, Wb, Wob);
    k1_mfma<<<1024, 256, 0, stream>>>(x, Wb, block_norm, in_proj_w, dt_bias, xbc, dtb);
    k3a_ssd<<<2048, 256, 0, stream>>>(xbc, dtb, conv_w, conv_b, A_log, D, ybf, h0b, cdec, Cp);
    k3b_chunkscan<<<128, 256, 0, stream>>>(h0b, cdec);
    k4_out<<<512, 256, 0, stream>>>(ybf, norm_gate, Wob, Wb, block_norm, x, h0b, cdec, Cp, out);
}